// Round 1
// baseline (1708.327 us; speedup 1.0000x reference)
//
#include <hip/hip_runtime.h>

#define N_NODES 100000
#define N_EDGES 1600000
#define IN_CH 256
#define HID 128
#define K_STEPS 10
#define ALPHA 0.1f
#define SCAN_BS 512

// ---------------- CSR build ----------------

static __global__ void zero_kernel(int* __restrict__ p, int n) {
    int i = blockIdx.x * blockDim.x + threadIdx.x;
    if (i < n) p[i] = 0;
}

static __global__ void degree_kernel(const int* __restrict__ src, const int* __restrict__ dst,
                                     int* __restrict__ deg_out, int* __restrict__ deg_in) {
    int e = blockIdx.x * blockDim.x + threadIdx.x;
    if (e < N_EDGES) {
        atomicAdd(&deg_out[src[e]], 1);
        atomicAdd(&deg_in[dst[e]], 1);
    }
}

static __global__ void inv_kernel(const int* __restrict__ deg_in, const int* __restrict__ deg_out,
                                  float* __restrict__ inv_in, float* __restrict__ inv_out) {
    int i = blockIdx.x * blockDim.x + threadIdx.x;
    if (i < N_NODES) {
        int di = deg_in[i], dO = deg_out[i];
        inv_in[i]  = di > 0 ? rsqrtf((float)di) : 0.f;
        inv_out[i] = dO > 0 ? rsqrtf((float)dO) : 0.f;
    }
}

// inclusive scan of deg_in into out1 (= row_ptr+1), block partials
static __global__ void scan_block_kernel(const int* __restrict__ in, int* __restrict__ out1,
                                         int* __restrict__ bsums) {
    __shared__ int s[SCAN_BS];
    int tid = threadIdx.x;
    int i = blockIdx.x * SCAN_BS + tid;
    int v = (i < N_NODES) ? in[i] : 0;
    s[tid] = v;
    __syncthreads();
    for (int o = 1; o < SCAN_BS; o <<= 1) {
        int t = (tid >= o) ? s[tid - o] : 0;
        __syncthreads();
        s[tid] += t;
        __syncthreads();
    }
    if (i < N_NODES) out1[i] = s[tid];
    if (tid == SCAN_BS - 1) bsums[blockIdx.x] = s[tid];
}

static __global__ void scan_sums_kernel(int* __restrict__ bsums, int nb) {
    __shared__ int s[256];
    int tid = threadIdx.x;
    int v = (tid < nb) ? bsums[tid] : 0;
    s[tid] = v;
    __syncthreads();
    for (int o = 1; o < 256; o <<= 1) {
        int t = (tid >= o) ? s[tid - o] : 0;
        __syncthreads();
        s[tid] += t;
        __syncthreads();
    }
    if (tid < nb) bsums[tid] = s[tid];
}

static __global__ void scan_add_kernel(int* __restrict__ out1, const int* __restrict__ bsums,
                                       int* __restrict__ row_ptr0) {
    int b = blockIdx.x;
    int i = b * SCAN_BS + threadIdx.x;
    if (b > 0 && i < N_NODES) out1[i] += bsums[b - 1];
    if (b == 0 && threadIdx.x == 0) row_ptr0[0] = 0;
}

static __global__ void cursor_copy_kernel(const int* __restrict__ row_ptr, int* __restrict__ cursor) {
    int i = blockIdx.x * blockDim.x + threadIdx.x;
    if (i < N_NODES) cursor[i] = row_ptr[i];
}

static __global__ void fill_kernel(const int* __restrict__ src, const int* __restrict__ dst,
                                   const float* __restrict__ inv_in, const float* __restrict__ inv_out,
                                   int* __restrict__ cursor, int* __restrict__ csr_src,
                                   float* __restrict__ csr_w) {
    int e = blockIdx.x * blockDim.x + threadIdx.x;
    if (e < N_EDGES) {
        int s = src[e], d = dst[e];
        int p = atomicAdd(&cursor[d], 1);
        csr_src[p] = s;
        csr_w[p] = inv_out[s] * inv_in[d];
    }
}

// ---------------- GEMM: C[N,128] = A[N,256] @ B[256,128], fp32 ----------------

static __global__ __launch_bounds__(256) void gemm_kernel(const float* __restrict__ A,
                                                          const float* __restrict__ B,
                                                          float* __restrict__ C) {
    __shared__ float As[32][68];    // k-major A tile, +4 pad keeps float4 alignment
    __shared__ float Bs[32][128];
    int tid = threadIdx.x;
    int brow = blockIdx.x * 64;
    int tc = tid & 31, tr = tid >> 5;
    float acc[8][4] = {};
    for (int k0 = 0; k0 < IN_CH; k0 += 32) {
#pragma unroll
        for (int i = 0; i < 2; i++) {
            int l = (tid + i * 256) * 4;     // 0..2047
            int r = l >> 5;                  // 0..63
            int kk = l & 31;
            float4 a = make_float4(0.f, 0.f, 0.f, 0.f);
            int grow = brow + r;
            if (grow < N_NODES) a = *(const float4*)&A[(size_t)grow * IN_CH + k0 + kk];
            As[kk + 0][r] = a.x;
            As[kk + 1][r] = a.y;
            As[kk + 2][r] = a.z;
            As[kk + 3][r] = a.w;
        }
#pragma unroll
        for (int i = 0; i < 4; i++) {
            int l = (tid + i * 256) * 4;     // 0..4095
            int kk = l >> 7;
            int cc = l & 127;
            *(float4*)&Bs[kk][cc] = *(const float4*)&B[(size_t)(k0 + kk) * HID + cc];
        }
        __syncthreads();
#pragma unroll
        for (int kk = 0; kk < 32; kk++) {
            float4 b4 = *(const float4*)&Bs[kk][tc * 4];
            float4 a0 = *(const float4*)&As[kk][tr * 8];
            float4 a1 = *(const float4*)&As[kk][tr * 8 + 4];
            float av[8] = {a0.x, a0.y, a0.z, a0.w, a1.x, a1.y, a1.z, a1.w};
#pragma unroll
            for (int i = 0; i < 8; i++) {
                acc[i][0] += av[i] * b4.x;
                acc[i][1] += av[i] * b4.y;
                acc[i][2] += av[i] * b4.z;
                acc[i][3] += av[i] * b4.w;
            }
        }
        __syncthreads();
    }
#pragma unroll
    for (int i = 0; i < 8; i++) {
        int grow = brow + tr * 8 + i;
        if (grow < N_NODES) *(float4*)&C[(size_t)grow * HID + tc * 4] = *(float4*)&acc[i][0];
    }
}

// ---------------- Propagation: wave-per-node, dst-centric CSR ----------------
// MODE 0: hout = relu(prop(hin) + bias)      (GraphConv epilogue)
// MODE 1: hout = (1-ALPHA)*prop(hin) + ALPHA*h0   (APPNP step)
template <int MODE>
static __global__ __launch_bounds__(256) void prop_kernel(const float* __restrict__ hin,
                                                          const int* __restrict__ rp,
                                                          const int* __restrict__ cs,
                                                          const float* __restrict__ cw,
                                                          const float* __restrict__ bias,
                                                          const float* __restrict__ h0,
                                                          float* __restrict__ hout) {
    int wid = (int)((blockIdx.x * (unsigned)blockDim.x + threadIdx.x) >> 6);
    if (wid >= N_NODES) return;
    int lane = threadIdx.x & 63;
    int c0 = lane * 2;
    int s = rp[wid], e = rp[wid + 1];
    float ax = 0.f, ay = 0.f;
    int j = s;
    for (; j + 2 <= e; j += 2) {
        int s0 = cs[j], s1 = cs[j + 1];
        float w0 = cw[j], w1 = cw[j + 1];
        float2 v0 = *(const float2*)&hin[(size_t)s0 * HID + c0];
        float2 v1 = *(const float2*)&hin[(size_t)s1 * HID + c0];
        ax += w0 * v0.x;
        ay += w0 * v0.y;
        ax += w1 * v1.x;
        ay += w1 * v1.y;
    }
    if (j < e) {
        int s0 = cs[j];
        float w0 = cw[j];
        float2 v0 = *(const float2*)&hin[(size_t)s0 * HID + c0];
        ax += w0 * v0.x;
        ay += w0 * v0.y;
    }
    float ox, oy;
    if (MODE == 0) {
        ox = fmaxf(ax + bias[c0], 0.f);
        oy = fmaxf(ay + bias[c0 + 1], 0.f);
    } else {
        float2 h00 = *(const float2*)&h0[(size_t)wid * HID + c0];
        ox = (1.f - ALPHA) * ax + ALPHA * h00.x;
        oy = (1.f - ALPHA) * ay + ALPHA * h00.y;
    }
    *(float2*)&hout[(size_t)wid * HID + c0] = make_float2(ox, oy);
}

// ---------------- launch ----------------

extern "C" void kernel_launch(void* const* d_in, const int* in_sizes, int n_in,
                              void* d_out, int out_size, void* d_ws, size_t ws_size,
                              hipStream_t stream) {
    const float* features = (const float*)d_in[0];
    const float* W = (const float*)d_in[1];
    const float* b = (const float*)d_in[2];
    const int* edge_index = (const int*)d_in[3];
    const int* src = edge_index;
    const int* dst = edge_index + N_EDGES;
    float* out = (float*)d_out;

    char* ws = (char*)d_ws;
    size_t off = 0;
    auto alloc = [&](size_t bytes) -> void* {
        void* p = ws + off;
        off = (off + bytes + 255) & ~(size_t)255;
        return p;
    };
    int* deg_in = (int*)alloc(N_NODES * 4);
    int* deg_out = (int*)alloc(N_NODES * 4);
    float* inv_in = (float*)alloc(N_NODES * 4);
    float* inv_out = (float*)alloc(N_NODES * 4);
    int* row_ptr = (int*)alloc((N_NODES + 1) * 4);
    int* cursor = (int*)alloc(N_NODES * 4);
    int* bsums = (int*)alloc(1024 * 4);
    int* csr_src = (int*)alloc((size_t)N_EDGES * 4);
    float* csr_w = (float*)alloc((size_t)N_EDGES * 4);
    float* tmpT = (float*)alloc((size_t)N_NODES * HID * 4);
    float* h0 = (float*)alloc((size_t)N_NODES * HID * 4);

    int nb = (N_NODES + 255) / 256;
    int eb = (N_EDGES + 255) / 256;
    int sb = (N_NODES + SCAN_BS - 1) / SCAN_BS;   // 196

    zero_kernel<<<nb, 256, 0, stream>>>(deg_in, N_NODES);
    zero_kernel<<<nb, 256, 0, stream>>>(deg_out, N_NODES);
    degree_kernel<<<eb, 256, 0, stream>>>(src, dst, deg_out, deg_in);
    inv_kernel<<<nb, 256, 0, stream>>>(deg_in, deg_out, inv_in, inv_out);
    scan_block_kernel<<<sb, SCAN_BS, 0, stream>>>(deg_in, row_ptr + 1, bsums);
    scan_sums_kernel<<<1, 256, 0, stream>>>(bsums, sb);
    scan_add_kernel<<<sb, SCAN_BS, 0, stream>>>(row_ptr + 1, bsums, row_ptr);
    cursor_copy_kernel<<<nb, 256, 0, stream>>>(row_ptr, cursor);
    fill_kernel<<<eb, 256, 0, stream>>>(src, dst, inv_in, inv_out, cursor, csr_src, csr_w);

    gemm_kernel<<<(N_NODES + 63) / 64, 256, 0, stream>>>(features, W, tmpT);

    int pb = (int)(((size_t)N_NODES * 64 + 255) / 256);   // one wave per node
    prop_kernel<0><<<pb, 256, 0, stream>>>(tmpT, row_ptr, csr_src, csr_w, b, nullptr, h0);

    const float* cur = h0;
    float* bufs[2] = {tmpT, out};
    for (int t = 0; t < K_STEPS; t++) {
        float* o = bufs[t & 1];          // t=9 (last, odd) lands in d_out
        prop_kernel<1><<<pb, 256, 0, stream>>>(cur, row_ptr, csr_src, csr_w, nullptr, h0, o);
        cur = o;
    }
}

// Round 2
// 1611.303 us; speedup vs baseline: 1.0602x; 1.0602x over previous
//
#include <hip/hip_runtime.h>

#define N_NODES 100000
#define N_EDGES 1600000
#define IN_CH 256
#define HID 128
#define K_STEPS 10
#define ALPHA 0.1f
#define SCAN_BS 512

// ---------------- CSR build ----------------

static __global__ void zero_kernel(int* __restrict__ p, int n) {
    int i = blockIdx.x * blockDim.x + threadIdx.x;
    if (i < n) p[i] = 0;
}

static __global__ void degree_kernel(const int* __restrict__ src, const int* __restrict__ dst,
                                     int* __restrict__ deg_out, int* __restrict__ deg_in) {
    int e = blockIdx.x * blockDim.x + threadIdx.x;
    if (e < N_EDGES) {
        atomicAdd(&deg_out[src[e]], 1);
        atomicAdd(&deg_in[dst[e]], 1);
    }
}

static __global__ void inv_kernel(const int* __restrict__ deg_in, const int* __restrict__ deg_out,
                                  float* __restrict__ inv_in, float* __restrict__ inv_out) {
    int i = blockIdx.x * blockDim.x + threadIdx.x;
    if (i < N_NODES) {
        int di = deg_in[i], dO = deg_out[i];
        inv_in[i]  = di > 0 ? rsqrtf((float)di) : 0.f;
        inv_out[i] = dO > 0 ? rsqrtf((float)dO) : 0.f;
    }
}

// inclusive scan of deg_in into out1 (= row_ptr+1), block partials
static __global__ void scan_block_kernel(const int* __restrict__ in, int* __restrict__ out1,
                                         int* __restrict__ bsums) {
    __shared__ int s[SCAN_BS];
    int tid = threadIdx.x;
    int i = blockIdx.x * SCAN_BS + tid;
    int v = (i < N_NODES) ? in[i] : 0;
    s[tid] = v;
    __syncthreads();
    for (int o = 1; o < SCAN_BS; o <<= 1) {
        int t = (tid >= o) ? s[tid - o] : 0;
        __syncthreads();
        s[tid] += t;
        __syncthreads();
    }
    if (i < N_NODES) out1[i] = s[tid];
    if (tid == SCAN_BS - 1) bsums[blockIdx.x] = s[tid];
}

static __global__ void scan_sums_kernel(int* __restrict__ bsums, int nb) {
    __shared__ int s[256];
    int tid = threadIdx.x;
    int v = (tid < nb) ? bsums[tid] : 0;
    s[tid] = v;
    __syncthreads();
    for (int o = 1; o < 256; o <<= 1) {
        int t = (tid >= o) ? s[tid - o] : 0;
        __syncthreads();
        s[tid] += t;
        __syncthreads();
    }
    if (tid < nb) bsums[tid] = s[tid];
}

static __global__ void scan_add_kernel(int* __restrict__ out1, const int* __restrict__ bsums,
                                       int* __restrict__ row_ptr0) {
    int b = blockIdx.x;
    int i = b * SCAN_BS + threadIdx.x;
    if (b > 0 && i < N_NODES) out1[i] += bsums[b - 1];
    if (b == 0 && threadIdx.x == 0) row_ptr0[0] = 0;
}

static __global__ void cursor_copy_kernel(const int* __restrict__ row_ptr, int* __restrict__ cursor) {
    int i = blockIdx.x * blockDim.x + threadIdx.x;
    if (i < N_NODES) cursor[i] = row_ptr[i];
}

static __global__ void fill_kernel(const int* __restrict__ src, const int* __restrict__ dst,
                                   const float* __restrict__ inv_in, const float* __restrict__ inv_out,
                                   int* __restrict__ cursor, int2* __restrict__ csr) {
    int e = blockIdx.x * blockDim.x + threadIdx.x;
    if (e < N_EDGES) {
        int s = src[e], d = dst[e];
        int p = atomicAdd(&cursor[d], 1);
        float w = inv_out[s] * inv_in[d];
        csr[p] = make_int2(s, __float_as_int(w));
    }
}

// ---------------- GEMM: C[N,128] = A[N,256] @ B[256,128], fp32 ----------------

static __global__ __launch_bounds__(256) void gemm_kernel(const float* __restrict__ A,
                                                          const float* __restrict__ B,
                                                          float* __restrict__ C) {
    __shared__ float As[32][68];    // k-major A tile, +4 pad keeps float4 alignment
    __shared__ float Bs[32][128];
    int tid = threadIdx.x;
    int brow = blockIdx.x * 64;
    int tc = tid & 31, tr = tid >> 5;
    float acc[8][4] = {};
    for (int k0 = 0; k0 < IN_CH; k0 += 32) {
#pragma unroll
        for (int i = 0; i < 2; i++) {
            int l = (tid + i * 256) * 4;     // 0..2047
            int r = l >> 5;                  // 0..63
            int kk = l & 31;
            float4 a = make_float4(0.f, 0.f, 0.f, 0.f);
            int grow = brow + r;
            if (grow < N_NODES) a = *(const float4*)&A[(size_t)grow * IN_CH + k0 + kk];
            As[kk + 0][r] = a.x;
            As[kk + 1][r] = a.y;
            As[kk + 2][r] = a.z;
            As[kk + 3][r] = a.w;
        }
#pragma unroll
        for (int i = 0; i < 4; i++) {
            int l = (tid + i * 256) * 4;     // 0..4095
            int kk = l >> 7;
            int cc = l & 127;
            *(float4*)&Bs[kk][cc] = *(const float4*)&B[(size_t)(k0 + kk) * HID + cc];
        }
        __syncthreads();
#pragma unroll
        for (int kk = 0; kk < 32; kk++) {
            float4 b4 = *(const float4*)&Bs[kk][tc * 4];
            float4 a0 = *(const float4*)&As[kk][tr * 8];
            float4 a1 = *(const float4*)&As[kk][tr * 8 + 4];
            float av[8] = {a0.x, a0.y, a0.z, a0.w, a1.x, a1.y, a1.z, a1.w};
#pragma unroll
            for (int i = 0; i < 8; i++) {
                acc[i][0] += av[i] * b4.x;
                acc[i][1] += av[i] * b4.y;
                acc[i][2] += av[i] * b4.z;
                acc[i][3] += av[i] * b4.w;
            }
        }
        __syncthreads();
    }
#pragma unroll
    for (int i = 0; i < 8; i++) {
        int grow = brow + tr * 8 + i;
        if (grow < N_NODES) *(float4*)&C[(size_t)grow * HID + tc * 4] = *(float4*)&acc[i][0];
    }
}

// ---------------- Propagation: wave-per-node, dst-centric CSR ----------------
// Wave layout: lanes 0-31 process even edge slots, lanes 32-63 odd slots.
// Each lane gathers float4 (32 lanes x 16B = 512B row). Halves combined via
// __shfl_xor(32) at the end.
// MODE 0: hout = relu(prop(hin) + bias)          (GraphConv epilogue)
// MODE 1: hout = (1-ALPHA)*prop(hin) + ALPHA*h0  (APPNP step)
template <int MODE>
static __global__ __launch_bounds__(256) void prop_kernel(const float* __restrict__ hin,
                                                          const int* __restrict__ rp,
                                                          const int2* __restrict__ csr,
                                                          const float* __restrict__ bias,
                                                          const float* __restrict__ h0,
                                                          float* __restrict__ hout) {
    int wid = (int)((blockIdx.x * (unsigned)blockDim.x + threadIdx.x) >> 6);
    if (wid >= N_NODES) return;
    int lane = threadIdx.x & 63;
    int half = lane >> 5;        // edge slot parity
    int cl = lane & 31;          // column lane
    int c0 = cl * 4;
    int s = rp[wid], e = rp[wid + 1];

    float ax = 0.f, ay = 0.f, az = 0.f, aw = 0.f;
    int j = s + half;
    // 2x unrolled: edges j and j+2 in flight per half-wave (4 per wave)
    for (; j + 2 < e; j += 4) {
        int2 iw0 = csr[j];
        int2 iw1 = csr[j + 2];
        float w0 = __int_as_float(iw0.y);
        float w1 = __int_as_float(iw1.y);
        float4 v0 = *(const float4*)&hin[(size_t)iw0.x * HID + c0];
        float4 v1 = *(const float4*)&hin[(size_t)iw1.x * HID + c0];
        ax += w0 * v0.x; ay += w0 * v0.y; az += w0 * v0.z; aw += w0 * v0.w;
        ax += w1 * v1.x; ay += w1 * v1.y; az += w1 * v1.z; aw += w1 * v1.w;
    }
    if (j < e) {
        int2 iw0 = csr[j];
        float w0 = __int_as_float(iw0.y);
        float4 v0 = *(const float4*)&hin[(size_t)iw0.x * HID + c0];
        ax += w0 * v0.x; ay += w0 * v0.y; az += w0 * v0.z; aw += w0 * v0.w;
    }

    // combine the two edge-slot halves (lane i <-> lane i+32)
    ax += __shfl_xor(ax, 32);
    ay += __shfl_xor(ay, 32);
    az += __shfl_xor(az, 32);
    aw += __shfl_xor(aw, 32);

    if (half == 0) {
        float4 o;
        if (MODE == 0) {
            float4 bb = *(const float4*)&bias[c0];
            o.x = fmaxf(ax + bb.x, 0.f);
            o.y = fmaxf(ay + bb.y, 0.f);
            o.z = fmaxf(az + bb.z, 0.f);
            o.w = fmaxf(aw + bb.w, 0.f);
        } else {
            float4 h00 = *(const float4*)&h0[(size_t)wid * HID + c0];
            o.x = (1.f - ALPHA) * ax + ALPHA * h00.x;
            o.y = (1.f - ALPHA) * ay + ALPHA * h00.y;
            o.z = (1.f - ALPHA) * az + ALPHA * h00.z;
            o.w = (1.f - ALPHA) * aw + ALPHA * h00.w;
        }
        *(float4*)&hout[(size_t)wid * HID + c0] = o;
    }
}

// ---------------- launch ----------------

extern "C" void kernel_launch(void* const* d_in, const int* in_sizes, int n_in,
                              void* d_out, int out_size, void* d_ws, size_t ws_size,
                              hipStream_t stream) {
    const float* features = (const float*)d_in[0];
    const float* W = (const float*)d_in[1];
    const float* b = (const float*)d_in[2];
    const int* edge_index = (const int*)d_in[3];
    const int* src = edge_index;
    const int* dst = edge_index + N_EDGES;
    float* out = (float*)d_out;

    char* ws = (char*)d_ws;
    size_t off = 0;
    auto alloc = [&](size_t bytes) -> void* {
        void* p = ws + off;
        off = (off + bytes + 255) & ~(size_t)255;
        return p;
    };
    int* deg_in = (int*)alloc(N_NODES * 4);
    int* deg_out = (int*)alloc(N_NODES * 4);
    float* inv_in = (float*)alloc(N_NODES * 4);
    float* inv_out = (float*)alloc(N_NODES * 4);
    int* row_ptr = (int*)alloc((N_NODES + 1) * 4);
    int* cursor = (int*)alloc(N_NODES * 4);
    int* bsums = (int*)alloc(1024 * 4);
    int2* csr = (int2*)alloc((size_t)N_EDGES * 8);
    float* tmpT = (float*)alloc((size_t)N_NODES * HID * 4);
    float* h0 = (float*)alloc((size_t)N_NODES * HID * 4);

    int nb = (N_NODES + 255) / 256;
    int eb = (N_EDGES + 255) / 256;
    int sb = (N_NODES + SCAN_BS - 1) / SCAN_BS;   // 196

    zero_kernel<<<nb, 256, 0, stream>>>(deg_in, N_NODES);
    zero_kernel<<<nb, 256, 0, stream>>>(deg_out, N_NODES);
    degree_kernel<<<eb, 256, 0, stream>>>(src, dst, deg_out, deg_in);
    inv_kernel<<<nb, 256, 0, stream>>>(deg_in, deg_out, inv_in, inv_out);
    scan_block_kernel<<<sb, SCAN_BS, 0, stream>>>(deg_in, row_ptr + 1, bsums);
    scan_sums_kernel<<<1, 256, 0, stream>>>(bsums, sb);
    scan_add_kernel<<<sb, SCAN_BS, 0, stream>>>(row_ptr + 1, bsums, row_ptr);
    cursor_copy_kernel<<<nb, 256, 0, stream>>>(row_ptr, cursor);
    fill_kernel<<<eb, 256, 0, stream>>>(src, dst, inv_in, inv_out, cursor, csr);

    gemm_kernel<<<(N_NODES + 63) / 64, 256, 0, stream>>>(features, W, tmpT);

    int pb = (int)(((size_t)N_NODES * 64 + 255) / 256);   // one wave per node
    prop_kernel<0><<<pb, 256, 0, stream>>>(tmpT, row_ptr, csr, b, nullptr, h0);

    const float* cur = h0;
    float* bufs[2] = {tmpT, out};
    for (int t = 0; t < K_STEPS; t++) {
        float* o = bufs[t & 1];          // t=9 (last, odd) lands in d_out
        prop_kernel<1><<<pb, 256, 0, stream>>>(cur, row_ptr, csr, nullptr, h0, o);
        cur = o;
    }
}

// Round 3
// 1590.326 us; speedup vs baseline: 1.0742x; 1.0132x over previous
//
#include <hip/hip_runtime.h>
#include <stdint.h>

#define N_NODES 100000
#define N_EDGES 1600000
#define IN_CH 256
#define HID 128
#define K_STEPS 10
#define ALPHA 0.1f

// dst bucketing
#define BKT_BITS 9
#define BKT_SIZE 512
#define NBKT 196                         // ceil(100000/512)
#define HBLK 256                         // blocks for hist/scatter
#define EPB (N_EDGES / HBLK)             // 6250 edges per block

// src-degree histogram partitioning
#define DR 8                             // node ranges
#define DRS (N_NODES / DR)               // 12500 nodes per range
#define DC 32                            // edge chunks
#define DCE (N_EDGES / DC)               // 50000 edges per chunk

// ---------------- K1: per-block bucket histogram (dst) ----------------
static __global__ __launch_bounds__(256) void bucket_hist_kernel(const int* __restrict__ dst,
                                                                 uint32_t* __restrict__ partials) {
    __shared__ uint32_t h[NBKT];
    int b = blockIdx.x, t = threadIdx.x;
    if (t < NBKT) h[t] = 0;
    __syncthreads();
    int base = b * EPB;
    for (int i = t; i < EPB; i += 256)
        atomicAdd(&h[(unsigned)dst[base + i] >> BKT_BITS], 1u);
    __syncthreads();
    if (t < NBKT) partials[t * HBLK + b] = h[t];          // [bucket][block]
}

// ---------------- K2a: src-degree partial histograms (LDS, range-partitioned) ----------------
static __global__ __launch_bounds__(256) void srcdeg_hist_kernel(const int* __restrict__ src,
                                                                 uint16_t* __restrict__ srcpart) {
    __shared__ uint32_t h[DRS];                            // 50 KB
    int r = blockIdx.x >> 5;                               // range 0..7
    int c = blockIdx.x & 31;                               // chunk 0..31
    int t = threadIdx.x;
    for (int i = t; i < DRS; i += 256) h[i] = 0;
    __syncthreads();
    int lo = r * DRS;
    int base = c * DCE;
    for (int i = t; i < DCE; i += 256) {
        unsigned sl = (unsigned)(src[base + i] - lo);
        if (sl < DRS) atomicAdd(&h[sl], 1u);
    }
    __syncthreads();
    for (int i = t; i < DRS; i += 256)
        srcpart[(size_t)c * N_NODES + lo + i] = (uint16_t)h[i];
}

// ---------------- K2b: reduce partials -> inv_out ----------------
static __global__ void srcdeg_reduce_kernel(const uint16_t* __restrict__ srcpart,
                                            float* __restrict__ inv_out) {
    int n = blockIdx.x * 256 + threadIdx.x;
    if (n >= N_NODES) return;
    uint32_t d = 0;
#pragma unroll
    for (int c = 0; c < DC; c++) d += srcpart[(size_t)c * N_NODES + n];
    inv_out[n] = d ? rsqrtf((float)d) : 0.f;
}

// ---------------- K3a: per-bucket totals ----------------
static __global__ __launch_bounds__(64) void bucket_totals_kernel(const uint32_t* __restrict__ partials,
                                                                  uint32_t* __restrict__ totals) {
    int k = blockIdx.x, t = threadIdx.x;
    const uint32_t* row = partials + (size_t)k * HBLK;
    uint32_t s = row[t] + row[t + 64] + row[t + 128] + row[t + 192];
#pragma unroll
    for (int o = 32; o; o >>= 1) s += __shfl_down(s, o);
    if (t == 0) totals[k] = s;
}

// ---------------- K3c: bucket bases + per-(bucket,block) cursors ----------------
static __global__ __launch_bounds__(256) void bucket_cursor_kernel(const uint32_t* __restrict__ partials,
                                                                   const uint32_t* __restrict__ totals,
                                                                   uint32_t* __restrict__ blockCursor,
                                                                   uint32_t* __restrict__ bucket_base) {
    __shared__ uint32_t sc[256];
    int k = blockIdx.x, t = threadIdx.x;
    uint32_t tk = (t < NBKT) ? totals[t] : 0;
    sc[t] = tk;
    __syncthreads();
    for (int o = 1; o < 256; o <<= 1) {
        uint32_t u = (t >= o) ? sc[t - o] : 0;
        __syncthreads();
        sc[t] += u;
        __syncthreads();
    }
    uint32_t incl_k = sc[k];
    uint32_t total_k = totals[k];
    uint32_t base = incl_k - total_k;                      // exclusive scan at k (wave-uniform)
    if (t == 0) {
        bucket_base[k] = base;
        if (k == NBKT - 1) bucket_base[NBKT] = incl_k;     // = N_EDGES
    }
    __syncthreads();
    uint32_t p = partials[(size_t)k * HBLK + t];
    sc[t] = p;
    __syncthreads();
    for (int o = 1; o < 256; o <<= 1) {
        uint32_t u = (t >= o) ? sc[t - o] : 0;
        __syncthreads();
        sc[t] += u;
        __syncthreads();
    }
    blockCursor[(size_t)k * HBLK + t] = base + sc[t] - p;  // exclusive over blocks
}

// ---------------- K4: scatter edges into bucket-ordered ebuf (LDS cursors) ----------------
static __global__ __launch_bounds__(256) void bucket_scatter_kernel(const int* __restrict__ src,
                                                                    const int* __restrict__ dst,
                                                                    const uint32_t* __restrict__ blockCursor,
                                                                    int2* __restrict__ ebuf) {
    __shared__ uint32_t cur[NBKT];
    int b = blockIdx.x, t = threadIdx.x;
    if (t < NBKT) cur[t] = blockCursor[(size_t)t * HBLK + b];
    __syncthreads();
    int base = b * EPB;
    for (int i = t; i < EPB; i += 256) {
        int s = src[base + i], d = dst[base + i];
        uint32_t p = atomicAdd(&cur[(unsigned)d >> BKT_BITS], 1u);
        ebuf[p] = make_int2(s, d);
    }
}

// ---------------- K5: per-bucket CSR build (row_ptr, weights, final csr) ----------------
static __global__ __launch_bounds__(256) void bucket_build_kernel(const int2* __restrict__ ebuf,
                                                                  const uint32_t* __restrict__ bucket_base,
                                                                  const float* __restrict__ inv_out,
                                                                  int* __restrict__ row_ptr,
                                                                  int2* __restrict__ csr) {
    __shared__ uint32_t h[BKT_SIZE];
    __shared__ uint32_t rs[BKT_SIZE];
    __shared__ float finv[BKT_SIZE];
    __shared__ uint32_t ps[256];
    int k = blockIdx.x, t = threadIdx.x;
    uint32_t b0 = bucket_base[k], b1 = bucket_base[k + 1];
    h[t] = 0; h[t + 256] = 0;
    __syncthreads();
    for (uint32_t i = b0 + t; i < b1; i += 256)
        atomicAdd(&h[ebuf[i].y & (BKT_SIZE - 1)], 1u);
    __syncthreads();
    uint32_t a = h[2 * t], bb = h[2 * t + 1];
    uint32_t pair = a + bb;
    ps[t] = pair;
    __syncthreads();
    for (int o = 1; o < 256; o <<= 1) {
        uint32_t u = (t >= o) ? ps[t - o] : 0;
        __syncthreads();
        ps[t] += u;
        __syncthreads();
    }
    uint32_t ex = ps[t] - pair;                             // exclusive pair start
    rs[2 * t] = ex;
    rs[2 * t + 1] = ex + a;
    finv[2 * t] = a ? rsqrtf((float)a) : 0.f;
    finv[2 * t + 1] = bb ? rsqrtf((float)bb) : 0.f;
    int node0 = k * BKT_SIZE;
    if (node0 + 2 * t < N_NODES) row_ptr[node0 + 2 * t] = (int)(b0 + ex);
    if (node0 + 2 * t + 1 < N_NODES) row_ptr[node0 + 2 * t + 1] = (int)(b0 + ex + a);
    if (k == NBKT - 1 && t == 0) row_ptr[N_NODES] = (int)b1;
    __syncthreads();
    for (uint32_t i = b0 + t; i < b1; i += 256) {
        int2 e = ebuf[i];
        int li = e.y & (BKT_SIZE - 1);
        uint32_t p = atomicAdd(&rs[li], 1u);                // local offset
        float w = inv_out[e.x] * finv[li];
        csr[b0 + p] = make_int2(e.x, __float_as_int(w));
    }
}

// ---------------- GEMM: C[N,128] = A[N,256] @ B[256,128], fp32 ----------------
static __global__ __launch_bounds__(256) void gemm_kernel(const float* __restrict__ A,
                                                          const float* __restrict__ B,
                                                          float* __restrict__ C) {
    __shared__ float As[32][68];
    __shared__ float Bs[32][128];
    int tid = threadIdx.x;
    int brow = blockIdx.x * 64;
    int tc = tid & 31, tr = tid >> 5;
    float acc[8][4] = {};
    for (int k0 = 0; k0 < IN_CH; k0 += 32) {
#pragma unroll
        for (int i = 0; i < 2; i++) {
            int l = (tid + i * 256) * 4;
            int r = l >> 5;
            int kk = l & 31;
            float4 a = make_float4(0.f, 0.f, 0.f, 0.f);
            int grow = brow + r;
            if (grow < N_NODES) a = *(const float4*)&A[(size_t)grow * IN_CH + k0 + kk];
            As[kk + 0][r] = a.x;
            As[kk + 1][r] = a.y;
            As[kk + 2][r] = a.z;
            As[kk + 3][r] = a.w;
        }
#pragma unroll
        for (int i = 0; i < 4; i++) {
            int l = (tid + i * 256) * 4;
            int kk = l >> 7;
            int cc = l & 127;
            *(float4*)&Bs[kk][cc] = *(const float4*)&B[(size_t)(k0 + kk) * HID + cc];
        }
        __syncthreads();
#pragma unroll
        for (int kk = 0; kk < 32; kk++) {
            float4 b4 = *(const float4*)&Bs[kk][tc * 4];
            float4 a0 = *(const float4*)&As[kk][tr * 8];
            float4 a1 = *(const float4*)&As[kk][tr * 8 + 4];
            float av[8] = {a0.x, a0.y, a0.z, a0.w, a1.x, a1.y, a1.z, a1.w};
#pragma unroll
            for (int i = 0; i < 8; i++) {
                acc[i][0] += av[i] * b4.x;
                acc[i][1] += av[i] * b4.y;
                acc[i][2] += av[i] * b4.z;
                acc[i][3] += av[i] * b4.w;
            }
        }
        __syncthreads();
    }
#pragma unroll
    for (int i = 0; i < 8; i++) {
        int grow = brow + tr * 8 + i;
        if (grow < N_NODES) *(float4*)&C[(size_t)grow * HID + tc * 4] = *(float4*)&acc[i][0];
    }
}

// ---------------- Propagation: wave-per-node, 4 edges in flight per half ----------------
template <int MODE>
static __global__ __launch_bounds__(256) void prop_kernel(const float* __restrict__ hin,
                                                          const int* __restrict__ rp,
                                                          const int2* __restrict__ csr,
                                                          const float* __restrict__ bias,
                                                          const float* __restrict__ h0,
                                                          float* __restrict__ hout) {
    int wid = (int)((blockIdx.x * (unsigned)blockDim.x + threadIdx.x) >> 6);
    if (wid >= N_NODES) return;
    int lane = threadIdx.x & 63;
    int half = lane >> 5;
    int c0 = (lane & 31) * 4;
    int s = rp[wid], e = rp[wid + 1];

    float ax = 0.f, ay = 0.f, az = 0.f, aw = 0.f;
    int j = s + half;
    for (; j + 6 < e; j += 8) {
        uint64_t r0 = __builtin_nontemporal_load((const uint64_t*)(csr + j));
        uint64_t r1 = __builtin_nontemporal_load((const uint64_t*)(csr + j + 2));
        uint64_t r2 = __builtin_nontemporal_load((const uint64_t*)(csr + j + 4));
        uint64_t r3 = __builtin_nontemporal_load((const uint64_t*)(csr + j + 6));
        int s0 = (int)(uint32_t)r0; float w0 = __uint_as_float((uint32_t)(r0 >> 32));
        int s1 = (int)(uint32_t)r1; float w1 = __uint_as_float((uint32_t)(r1 >> 32));
        int s2 = (int)(uint32_t)r2; float w2 = __uint_as_float((uint32_t)(r2 >> 32));
        int s3 = (int)(uint32_t)r3; float w3 = __uint_as_float((uint32_t)(r3 >> 32));
        float4 v0 = *(const float4*)&hin[(size_t)s0 * HID + c0];
        float4 v1 = *(const float4*)&hin[(size_t)s1 * HID + c0];
        float4 v2 = *(const float4*)&hin[(size_t)s2 * HID + c0];
        float4 v3 = *(const float4*)&hin[(size_t)s3 * HID + c0];
        ax += w0 * v0.x; ay += w0 * v0.y; az += w0 * v0.z; aw += w0 * v0.w;
        ax += w1 * v1.x; ay += w1 * v1.y; az += w1 * v1.z; aw += w1 * v1.w;
        ax += w2 * v2.x; ay += w2 * v2.y; az += w2 * v2.z; aw += w2 * v2.w;
        ax += w3 * v3.x; ay += w3 * v3.y; az += w3 * v3.z; aw += w3 * v3.w;
    }
    for (; j < e; j += 2) {
        uint64_t r0 = __builtin_nontemporal_load((const uint64_t*)(csr + j));
        int s0 = (int)(uint32_t)r0; float w0 = __uint_as_float((uint32_t)(r0 >> 32));
        float4 v0 = *(const float4*)&hin[(size_t)s0 * HID + c0];
        ax += w0 * v0.x; ay += w0 * v0.y; az += w0 * v0.z; aw += w0 * v0.w;
    }

    ax += __shfl_xor(ax, 32);
    ay += __shfl_xor(ay, 32);
    az += __shfl_xor(az, 32);
    aw += __shfl_xor(aw, 32);

    if (half == 0) {
        float4 o;
        if (MODE == 0) {
            float4 bb = *(const float4*)&bias[c0];
            o.x = fmaxf(ax + bb.x, 0.f);
            o.y = fmaxf(ay + bb.y, 0.f);
            o.z = fmaxf(az + bb.z, 0.f);
            o.w = fmaxf(aw + bb.w, 0.f);
        } else {
            float4 h00 = *(const float4*)&h0[(size_t)wid * HID + c0];
            o.x = (1.f - ALPHA) * ax + ALPHA * h00.x;
            o.y = (1.f - ALPHA) * ay + ALPHA * h00.y;
            o.z = (1.f - ALPHA) * az + ALPHA * h00.z;
            o.w = (1.f - ALPHA) * aw + ALPHA * h00.w;
        }
        *(float4*)&hout[(size_t)wid * HID + c0] = o;
    }
}

// ---------------- launch ----------------
extern "C" void kernel_launch(void* const* d_in, const int* in_sizes, int n_in,
                              void* d_out, int out_size, void* d_ws, size_t ws_size,
                              hipStream_t stream) {
    const float* features = (const float*)d_in[0];
    const float* W = (const float*)d_in[1];
    const float* b = (const float*)d_in[2];
    const int* edge_index = (const int*)d_in[3];
    const int* src = edge_index;
    const int* dst = edge_index + N_EDGES;
    float* out = (float*)d_out;

    char* ws = (char*)d_ws;
    size_t off = 0;
    auto alloc = [&](size_t bytes) -> void* {
        void* p = ws + off;
        off = (off + bytes + 255) & ~(size_t)255;
        return p;
    };
    // persistent
    int2* csr = (int2*)alloc((size_t)N_EDGES * 8);              // 12.8 MB
    float* tmpT = (float*)alloc((size_t)N_NODES * HID * 4);     // 51.2 MB
    float* h0 = (float*)alloc((size_t)N_NODES * HID * 4);       // 51.2 MB
    float* inv_out = (float*)alloc((size_t)N_NODES * 4);
    int* row_ptr = (int*)alloc((size_t)(N_NODES + 1) * 4);
    // transient (aliased over tmpT: consumed before gemm writes tmpT)
    char* tb = (char*)tmpT;
    size_t toff = 0;
    auto talloc = [&](size_t bytes) -> void* {
        void* p = tb + toff;
        toff = (toff + bytes + 255) & ~(size_t)255;
        return p;
    };
    int2* ebuf = (int2*)talloc((size_t)N_EDGES * 8);            // 12.8 MB
    uint16_t* srcpart = (uint16_t*)talloc((size_t)DC * N_NODES * 2);  // 6.4 MB
    uint32_t* partials = (uint32_t*)talloc((size_t)NBKT * HBLK * 4);
    uint32_t* blockCursor = (uint32_t*)talloc((size_t)NBKT * HBLK * 4);
    uint32_t* totals = (uint32_t*)talloc(NBKT * 4);
    uint32_t* bucket_base = (uint32_t*)talloc((NBKT + 1) * 4);

    bucket_hist_kernel<<<HBLK, 256, 0, stream>>>(dst, partials);
    srcdeg_hist_kernel<<<DR * DC, 256, 0, stream>>>(src, srcpart);
    srcdeg_reduce_kernel<<<(N_NODES + 255) / 256, 256, 0, stream>>>(srcpart, inv_out);
    bucket_totals_kernel<<<NBKT, 64, 0, stream>>>(partials, totals);
    bucket_cursor_kernel<<<NBKT, 256, 0, stream>>>(partials, totals, blockCursor, bucket_base);
    bucket_scatter_kernel<<<HBLK, 256, 0, stream>>>(src, dst, blockCursor, ebuf);
    bucket_build_kernel<<<NBKT, 256, 0, stream>>>(ebuf, bucket_base, inv_out, row_ptr, csr);

    gemm_kernel<<<(N_NODES + 63) / 64, 256, 0, stream>>>(features, W, tmpT);

    int pb = (int)(((size_t)N_NODES * 64) / 256);               // one wave per node
    prop_kernel<0><<<pb, 256, 0, stream>>>(tmpT, row_ptr, csr, b, nullptr, h0);

    const float* cur = h0;
    float* bufs[2] = {tmpT, out};
    for (int t = 0; t < K_STEPS; t++) {
        float* o = bufs[t & 1];                                 // t=9 (odd) lands in d_out
        prop_kernel<1><<<pb, 256, 0, stream>>>(cur, row_ptr, csr, nullptr, h0, o);
        cur = o;
    }
}

// Round 4
// 896.401 us; speedup vs baseline: 1.9058x; 1.7741x over previous
//
#include <hip/hip_runtime.h>
#include <hip/hip_fp16.h>
#include <stdint.h>

#define N_NODES 100000
#define N_EDGES 1600000
#define IN_CH 256
#define HID 128
#define K_STEPS 10
#define ALPHA 0.1f

// dst bucketing
#define BKT_BITS 9
#define BKT_SIZE 512
#define NBKT 196                         // ceil(100000/512)
#define HBLK 256                         // blocks for hist/scatter
#define EPB (N_EDGES / HBLK)             // 6250 edges per block

// src-degree histogram partitioning
#define DR 8                             // node ranges
#define DRS (N_NODES / DR)               // 12500 nodes per range
#define DC 32                            // edge chunks
#define DCE (N_EDGES / DC)               // 50000 edges per chunk

// ---------------- K1: per-block bucket histogram (dst) ----------------
static __global__ __launch_bounds__(256) void bucket_hist_kernel(const int* __restrict__ dst,
                                                                 uint32_t* __restrict__ partials) {
    __shared__ uint32_t h[NBKT];
    int b = blockIdx.x, t = threadIdx.x;
    if (t < NBKT) h[t] = 0;
    __syncthreads();
    int base = b * EPB;
    for (int i = t; i < EPB; i += 256)
        atomicAdd(&h[(unsigned)dst[base + i] >> BKT_BITS], 1u);
    __syncthreads();
    if (t < NBKT) partials[t * HBLK + b] = h[t];          // [bucket][block]
}

// ---------------- K2a: src-degree partial histograms ----------------
static __global__ __launch_bounds__(256) void srcdeg_hist_kernel(const int* __restrict__ src,
                                                                 uint16_t* __restrict__ srcpart) {
    __shared__ uint32_t h[DRS];                            // 50 KB
    int r = blockIdx.x >> 5;                               // range 0..7
    int c = blockIdx.x & 31;                               // chunk 0..31
    int t = threadIdx.x;
    for (int i = t; i < DRS; i += 256) h[i] = 0;
    __syncthreads();
    int lo = r * DRS;
    int base = c * DCE;
    for (int i = t; i < DCE; i += 256) {
        unsigned sl = (unsigned)(src[base + i] - lo);
        if (sl < DRS) atomicAdd(&h[sl], 1u);
    }
    __syncthreads();
    for (int i = t; i < DRS; i += 256)
        srcpart[(size_t)c * N_NODES + lo + i] = (uint16_t)h[i];
}

// ---------------- K2b: reduce partials -> inv_out ----------------
static __global__ void srcdeg_reduce_kernel(const uint16_t* __restrict__ srcpart,
                                            float* __restrict__ inv_out) {
    int n = blockIdx.x * 256 + threadIdx.x;
    if (n >= N_NODES) return;
    uint32_t d = 0;
#pragma unroll
    for (int c = 0; c < DC; c++) d += srcpart[(size_t)c * N_NODES + n];
    inv_out[n] = d ? rsqrtf((float)d) : 0.f;
}

// ---------------- K3a: per-bucket totals ----------------
static __global__ __launch_bounds__(64) void bucket_totals_kernel(const uint32_t* __restrict__ partials,
                                                                  uint32_t* __restrict__ totals) {
    int k = blockIdx.x, t = threadIdx.x;
    const uint32_t* row = partials + (size_t)k * HBLK;
    uint32_t s = row[t] + row[t + 64] + row[t + 128] + row[t + 192];
#pragma unroll
    for (int o = 32; o; o >>= 1) s += __shfl_down(s, o);
    if (t == 0) totals[k] = s;
}

// ---------------- K3c: bucket bases + per-(bucket,block) cursors ----------------
static __global__ __launch_bounds__(256) void bucket_cursor_kernel(const uint32_t* __restrict__ partials,
                                                                   const uint32_t* __restrict__ totals,
                                                                   uint32_t* __restrict__ blockCursor,
                                                                   uint32_t* __restrict__ bucket_base) {
    __shared__ uint32_t sc[256];
    int k = blockIdx.x, t = threadIdx.x;
    uint32_t tk = (t < NBKT) ? totals[t] : 0;
    sc[t] = tk;
    __syncthreads();
    for (int o = 1; o < 256; o <<= 1) {
        uint32_t u = (t >= o) ? sc[t - o] : 0;
        __syncthreads();
        sc[t] += u;
        __syncthreads();
    }
    uint32_t incl_k = sc[k];
    uint32_t total_k = totals[k];
    uint32_t base = incl_k - total_k;
    if (t == 0) {
        bucket_base[k] = base;
        if (k == NBKT - 1) bucket_base[NBKT] = incl_k;
    }
    __syncthreads();
    uint32_t p = partials[(size_t)k * HBLK + t];
    sc[t] = p;
    __syncthreads();
    for (int o = 1; o < 256; o <<= 1) {
        uint32_t u = (t >= o) ? sc[t - o] : 0;
        __syncthreads();
        sc[t] += u;
        __syncthreads();
    }
    blockCursor[(size_t)k * HBLK + t] = base + sc[t] - p;
}

// ---------------- K4: scatter edges into bucket-ordered ebuf ----------------
static __global__ __launch_bounds__(256) void bucket_scatter_kernel(const int* __restrict__ src,
                                                                    const int* __restrict__ dst,
                                                                    const uint32_t* __restrict__ blockCursor,
                                                                    int2* __restrict__ ebuf) {
    __shared__ uint32_t cur[NBKT];
    int b = blockIdx.x, t = threadIdx.x;
    if (t < NBKT) cur[t] = blockCursor[(size_t)t * HBLK + b];
    __syncthreads();
    int base = b * EPB;
    for (int i = t; i < EPB; i += 256) {
        int s = src[base + i], d = dst[base + i];
        uint32_t p = atomicAdd(&cur[(unsigned)d >> BKT_BITS], 1u);
        ebuf[p] = make_int2(s, d);
    }
}

// ---------------- K5: per-bucket CSR build (row_ptr, inv_in, csr src-only) ----------------
static __global__ __launch_bounds__(256) void bucket_build_kernel(const int2* __restrict__ ebuf,
                                                                  const uint32_t* __restrict__ bucket_base,
                                                                  int* __restrict__ row_ptr,
                                                                  float* __restrict__ inv_in,
                                                                  int* __restrict__ csr) {
    __shared__ uint32_t h[BKT_SIZE];
    __shared__ uint32_t rs[BKT_SIZE];
    __shared__ uint32_t ps[256];
    int k = blockIdx.x, t = threadIdx.x;
    uint32_t b0 = bucket_base[k], b1 = bucket_base[k + 1];
    h[t] = 0; h[t + 256] = 0;
    __syncthreads();
    for (uint32_t i = b0 + t; i < b1; i += 256)
        atomicAdd(&h[ebuf[i].y & (BKT_SIZE - 1)], 1u);
    __syncthreads();
    uint32_t a = h[2 * t], bb = h[2 * t + 1];
    uint32_t pair = a + bb;
    ps[t] = pair;
    __syncthreads();
    for (int o = 1; o < 256; o <<= 1) {
        uint32_t u = (t >= o) ? ps[t - o] : 0;
        __syncthreads();
        ps[t] += u;
        __syncthreads();
    }
    uint32_t ex = ps[t] - pair;
    rs[2 * t] = ex;
    rs[2 * t + 1] = ex + a;
    int node0 = k * BKT_SIZE;
    if (node0 + 2 * t < N_NODES) {
        row_ptr[node0 + 2 * t] = (int)(b0 + ex);
        inv_in[node0 + 2 * t] = a ? rsqrtf((float)a) : 0.f;
    }
    if (node0 + 2 * t + 1 < N_NODES) {
        row_ptr[node0 + 2 * t + 1] = (int)(b0 + ex + a);
        inv_in[node0 + 2 * t + 1] = bb ? rsqrtf((float)bb) : 0.f;
    }
    if (k == NBKT - 1 && t == 0) row_ptr[N_NODES] = (int)b1;
    __syncthreads();
    for (uint32_t i = b0 + t; i < b1; i += 256) {
        int2 e = ebuf[i];
        int li = e.y & (BKT_SIZE - 1);
        uint32_t p = atomicAdd(&rs[li], 1u);
        csr[b0 + p] = e.x;
    }
}

// ---------------- GEMM: t16[s] = fp16( (A@W)[s] * inv_out[s] ) ----------------
static __global__ __launch_bounds__(256) void gemm_kernel(const float* __restrict__ A,
                                                          const float* __restrict__ B,
                                                          const float* __restrict__ inv_out,
                                                          __half* __restrict__ t16) {
    __shared__ float As[32][68];
    __shared__ float Bs[32][128];
    int tid = threadIdx.x;
    int brow = blockIdx.x * 64;
    int tc = tid & 31, tr = tid >> 5;
    float acc[8][4] = {};
    for (int k0 = 0; k0 < IN_CH; k0 += 32) {
#pragma unroll
        for (int i = 0; i < 2; i++) {
            int l = (tid + i * 256) * 4;
            int r = l >> 5;
            int kk = l & 31;
            float4 a = make_float4(0.f, 0.f, 0.f, 0.f);
            int grow = brow + r;
            if (grow < N_NODES) a = *(const float4*)&A[(size_t)grow * IN_CH + k0 + kk];
            As[kk + 0][r] = a.x;
            As[kk + 1][r] = a.y;
            As[kk + 2][r] = a.z;
            As[kk + 3][r] = a.w;
        }
#pragma unroll
        for (int i = 0; i < 4; i++) {
            int l = (tid + i * 256) * 4;
            int kk = l >> 7;
            int cc = l & 127;
            *(float4*)&Bs[kk][cc] = *(const float4*)&B[(size_t)(k0 + kk) * HID + cc];
        }
        __syncthreads();
#pragma unroll
        for (int kk = 0; kk < 32; kk++) {
            float4 b4 = *(const float4*)&Bs[kk][tc * 4];
            float4 a0 = *(const float4*)&As[kk][tr * 8];
            float4 a1 = *(const float4*)&As[kk][tr * 8 + 4];
            float av[8] = {a0.x, a0.y, a0.z, a0.w, a1.x, a1.y, a1.z, a1.w};
#pragma unroll
            for (int i = 0; i < 8; i++) {
                acc[i][0] += av[i] * b4.x;
                acc[i][1] += av[i] * b4.y;
                acc[i][2] += av[i] * b4.z;
                acc[i][3] += av[i] * b4.w;
            }
        }
        __syncthreads();
    }
#pragma unroll
    for (int i = 0; i < 8; i++) {
        int grow = brow + tr * 8 + i;
        if (grow < N_NODES) {
            float sc = inv_out[grow];
            __half2 h01 = __floats2half2_rn(acc[i][0] * sc, acc[i][1] * sc);
            __half2 h23 = __floats2half2_rn(acc[i][2] * sc, acc[i][3] * sc);
            uint2 u;
            u.x = *(uint32_t*)&h01;
            u.y = *(uint32_t*)&h23;
            *(uint2*)&t16[(size_t)grow * HID + tc * 4] = u;
        }
    }
}

// ---------------- zero the sentinel row N in fp16 buffers ----------------
static __global__ void zero_rows_kernel(__half* a, __half* b, __half* c) {
    int t = threadIdx.x;                 // 64 threads, row = 64 u32
    ((uint32_t*)a)[(size_t)N_NODES * 64 + t] = 0;
    ((uint32_t*)b)[(size_t)N_NODES * 64 + t] = 0;
    ((uint32_t*)c)[(size_t)N_NODES * 64 + t] = 0;
}

// ---------------- Propagation, fp16 gathers ----------------
// Wave: 4 subgroups x 16 lanes; subgroup handles one edge; lane covers 8 cols.
// MODE 0: h0 = relu(inv_in*acc + bias); write h0h (fp16) + g0 = h0*inv_out (fp16)
// MODE 1: h = 0.9*inv_in*acc + 0.1*h0h; write g' = h*inv_out (fp16)
// MODE 2: same h; write fp32 out
template <int MODE>
static __global__ __launch_bounds__(256) void prop16_kernel(const __half* __restrict__ gin,
                                                            const int* __restrict__ rp,
                                                            const int* __restrict__ cs,
                                                            const float* __restrict__ inv_in,
                                                            const float* __restrict__ inv_out,
                                                            const float* __restrict__ bias,
                                                            const __half* __restrict__ h0h,
                                                            __half* __restrict__ gout,
                                                            __half* __restrict__ h0out,
                                                            float* __restrict__ fout) {
    int wid = (int)((blockIdx.x * 256u + threadIdx.x) >> 6);
    if (wid >= N_NODES) return;
    int lane = threadIdx.x & 63;
    int sub = lane >> 4;
    int cl = lane & 15;
    int s = rp[wid], e = rp[wid + 1];
    const uint4* g4 = (const uint4*)gin;          // 16 uint4 per row

    float a[8] = {};
    for (int j = s; j < e; j += 8) {
        int j0 = j + sub, j1 = j0 + 4;
        int v0 = cs[j0], v1 = cs[j1];             // csr alloc padded by 8
        int i0 = (j0 < e) ? v0 : N_NODES;
        int i1 = (j1 < e) ? v1 : N_NODES;
        uint4 u0 = g4[(size_t)i0 * 16 + cl];
        uint4 u1 = g4[(size_t)i1 * 16 + cl];
        const __half2* p0 = (const __half2*)&u0;
        const __half2* p1 = (const __half2*)&u1;
#pragma unroll
        for (int k = 0; k < 4; k++) {
            float2 f0 = __half22float2(p0[k]);
            float2 f1 = __half22float2(p1[k]);
            a[2 * k] += f0.x + f1.x;
            a[2 * k + 1] += f0.y + f1.y;
        }
    }
#pragma unroll
    for (int k = 0; k < 8; k++) {
        a[k] += __shfl_xor(a[k], 16);
        a[k] += __shfl_xor(a[k], 32);
    }
    if (sub != 0) return;
    int c0 = cl * 8;
    if (MODE == 0) {
        float ii = inv_in[wid], io = inv_out[wid];
        float4 b0 = *(const float4*)&bias[c0];
        float4 b1 = *(const float4*)&bias[c0 + 4];
        float h[8];
        h[0] = fmaxf(a[0] * ii + b0.x, 0.f);
        h[1] = fmaxf(a[1] * ii + b0.y, 0.f);
        h[2] = fmaxf(a[2] * ii + b0.z, 0.f);
        h[3] = fmaxf(a[3] * ii + b0.w, 0.f);
        h[4] = fmaxf(a[4] * ii + b1.x, 0.f);
        h[5] = fmaxf(a[5] * ii + b1.y, 0.f);
        h[6] = fmaxf(a[6] * ii + b1.z, 0.f);
        h[7] = fmaxf(a[7] * ii + b1.w, 0.f);
        __half2 hh[4], gg[4];
#pragma unroll
        for (int k = 0; k < 4; k++) {
            hh[k] = __floats2half2_rn(h[2 * k], h[2 * k + 1]);
            gg[k] = __floats2half2_rn(h[2 * k] * io, h[2 * k + 1] * io);
        }
        ((uint4*)h0out)[(size_t)wid * 16 + cl] = *(uint4*)hh;
        ((uint4*)gout)[(size_t)wid * 16 + cl] = *(uint4*)gg;
    } else {
        float ii = inv_in[wid] * (1.f - ALPHA);
        uint4 uh = ((const uint4*)h0h)[(size_t)wid * 16 + cl];
        const __half2* ph = (const __half2*)&uh;
        float h[8];
#pragma unroll
        for (int k = 0; k < 4; k++) {
            float2 f = __half22float2(ph[k]);
            h[2 * k] = a[2 * k] * ii + ALPHA * f.x;
            h[2 * k + 1] = a[2 * k + 1] * ii + ALPHA * f.y;
        }
        if (MODE == 1) {
            float io = inv_out[wid];
            __half2 gg[4];
#pragma unroll
            for (int k = 0; k < 4; k++)
                gg[k] = __floats2half2_rn(h[2 * k] * io, h[2 * k + 1] * io);
            ((uint4*)gout)[(size_t)wid * 16 + cl] = *(uint4*)gg;
        } else {
            *(float4*)&fout[(size_t)wid * HID + c0] = make_float4(h[0], h[1], h[2], h[3]);
            *(float4*)&fout[(size_t)wid * HID + c0 + 4] = make_float4(h[4], h[5], h[6], h[7]);
        }
    }
}

// ---------------- launch ----------------
extern "C" void kernel_launch(void* const* d_in, const int* in_sizes, int n_in,
                              void* d_out, int out_size, void* d_ws, size_t ws_size,
                              hipStream_t stream) {
    const float* features = (const float*)d_in[0];
    const float* W = (const float*)d_in[1];
    const float* b = (const float*)d_in[2];
    const int* edge_index = (const int*)d_in[3];
    const int* src = edge_index;
    const int* dst = edge_index + N_EDGES;
    float* out = (float*)d_out;

    char* ws = (char*)d_ws;
    size_t off = 0;
    auto alloc = [&](size_t bytes) -> void* {
        void* p = ws + off;
        off = (off + bytes + 255) & ~(size_t)255;
        return p;
    };
    // persistent
    int* csr = (int*)alloc(((size_t)N_EDGES + 8) * 4);              // 6.4 MB
    __half* t16 = (__half*)alloc((size_t)(N_NODES + 1) * HID * 2);  // 25.6 MB
    __half* gA  = (__half*)alloc((size_t)(N_NODES + 1) * HID * 2);  // 25.6 MB
    __half* gB  = (__half*)alloc((size_t)(N_NODES + 1) * HID * 2);  // 25.6 MB
    __half* h0h = (__half*)alloc((size_t)N_NODES * HID * 2);        // 25.6 MB
    float* inv_out = (float*)alloc((size_t)N_NODES * 4);
    float* inv_in = (float*)alloc((size_t)N_NODES * 4);
    int* row_ptr = (int*)alloc((size_t)(N_NODES + 1) * 4);
    // transient, aliased over gA+gB (consumed before first prop writes them)
    char* tb = (char*)gA;
    size_t toff = 0;
    auto talloc = [&](size_t bytes) -> void* {
        void* p = tb + toff;
        toff = (toff + bytes + 255) & ~(size_t)255;
        return p;
    };
    int2* ebuf = (int2*)talloc((size_t)N_EDGES * 8);                 // 12.8 MB
    uint16_t* srcpart = (uint16_t*)talloc((size_t)DC * N_NODES * 2); // 6.4 MB
    uint32_t* partials = (uint32_t*)talloc((size_t)NBKT * HBLK * 4);
    uint32_t* blockCursor = (uint32_t*)talloc((size_t)NBKT * HBLK * 4);
    uint32_t* totals = (uint32_t*)talloc(NBKT * 4);
    uint32_t* bucket_base = (uint32_t*)talloc((NBKT + 1) * 4);

    bucket_hist_kernel<<<HBLK, 256, 0, stream>>>(dst, partials);
    srcdeg_hist_kernel<<<DR * DC, 256, 0, stream>>>(src, srcpart);
    srcdeg_reduce_kernel<<<(N_NODES + 255) / 256, 256, 0, stream>>>(srcpart, inv_out);
    bucket_totals_kernel<<<NBKT, 64, 0, stream>>>(partials, totals);
    bucket_cursor_kernel<<<NBKT, 256, 0, stream>>>(partials, totals, blockCursor, bucket_base);
    bucket_scatter_kernel<<<HBLK, 256, 0, stream>>>(src, dst, blockCursor, ebuf);
    bucket_build_kernel<<<NBKT, 256, 0, stream>>>(ebuf, bucket_base, row_ptr, inv_in, csr);

    gemm_kernel<<<(N_NODES + 63) / 64, 256, 0, stream>>>(features, W, inv_out, t16);
    zero_rows_kernel<<<1, 64, 0, stream>>>(t16, gA, gB);

    int pb = (int)(((size_t)N_NODES * 64) / 256);
    // GraphConv epilogue: h0h + g0 (into gA)
    prop16_kernel<0><<<pb, 256, 0, stream>>>(t16, row_ptr, csr, inv_in, inv_out, b, nullptr,
                                             gA, h0h, nullptr);
    // APPNP steps 0..8 (fp16 ping-pong), step 9 writes fp32 out
    const __half* cur = gA;
    for (int t = 0; t < K_STEPS - 1; t++) {
        __half* nxt = (t & 1) ? gA : gB;
        prop16_kernel<1><<<pb, 256, 0, stream>>>(cur, row_ptr, csr, inv_in, inv_out, nullptr, h0h,
                                                 nxt, nullptr, nullptr);
        cur = nxt;
    }
    prop16_kernel<2><<<pb, 256, 0, stream>>>(cur, row_ptr, csr, inv_in, inv_out, nullptr, h0h,
                                             nullptr, nullptr, out);
}

// Round 5
// 838.379 us; speedup vs baseline: 2.0377x; 1.0692x over previous
//
#include <hip/hip_runtime.h>
#include <hip/hip_fp16.h>
#include <stdint.h>

#define N_NODES 100000
#define N_EDGES 1600000
#define IN_CH 256
#define HID 128
#define K_STEPS 10
#define ALPHA 0.1f

// dst bucketing
#define BKT_BITS 9
#define BKT_SIZE 512
#define NBKT 196                         // ceil(100000/512)
#define HBLK 256                         // blocks for hist/scatter
#define EPB (N_EDGES / HBLK)             // 6250 edges per block

// src-degree histogram partitioning
#define DR 8                             // node ranges
#define DRS (N_NODES / DR)               // 12500 nodes per range
#define DC 32                            // edge chunks
#define DCE (N_EDGES / DC)               // 50000 edges per chunk

typedef _Float16 f16x8 __attribute__((ext_vector_type(8)));
typedef float f32x4 __attribute__((ext_vector_type(4)));

// ---------------- K1: per-block bucket histogram (dst) ----------------
static __global__ __launch_bounds__(256) void bucket_hist_kernel(const int* __restrict__ dst,
                                                                 uint32_t* __restrict__ partials) {
    __shared__ uint32_t h[NBKT];
    int b = blockIdx.x, t = threadIdx.x;
    if (t < NBKT) h[t] = 0;
    __syncthreads();
    int base = b * EPB;
    for (int i = t; i < EPB; i += 256)
        atomicAdd(&h[(unsigned)dst[base + i] >> BKT_BITS], 1u);
    __syncthreads();
    if (t < NBKT) partials[t * HBLK + b] = h[t];          // [bucket][block]
}

// ---------------- K2a: src-degree partial histograms ----------------
static __global__ __launch_bounds__(256) void srcdeg_hist_kernel(const int* __restrict__ src,
                                                                 uint16_t* __restrict__ srcpart) {
    __shared__ uint32_t h[DRS];                            // 50 KB
    int r = blockIdx.x >> 5;                               // range 0..7
    int c = blockIdx.x & 31;                               // chunk 0..31
    int t = threadIdx.x;
    for (int i = t; i < DRS; i += 256) h[i] = 0;
    __syncthreads();
    int lo = r * DRS;
    int base = c * DCE;
    for (int i = t; i < DCE; i += 256) {
        unsigned sl = (unsigned)(src[base + i] - lo);
        if (sl < DRS) atomicAdd(&h[sl], 1u);
    }
    __syncthreads();
    for (int i = t; i < DRS; i += 256)
        srcpart[(size_t)c * N_NODES + lo + i] = (uint16_t)h[i];
}

// ---------------- K2b: reduce partials -> inv_out ----------------
static __global__ void srcdeg_reduce_kernel(const uint16_t* __restrict__ srcpart,
                                            float* __restrict__ inv_out) {
    int n = blockIdx.x * 256 + threadIdx.x;
    if (n >= N_NODES) return;
    uint32_t d = 0;
#pragma unroll
    for (int c = 0; c < DC; c++) d += srcpart[(size_t)c * N_NODES + n];
    inv_out[n] = d ? rsqrtf((float)d) : 0.f;
}

// ---------------- K3a: per-bucket totals ----------------
static __global__ __launch_bounds__(64) void bucket_totals_kernel(const uint32_t* __restrict__ partials,
                                                                  uint32_t* __restrict__ totals) {
    int k = blockIdx.x, t = threadIdx.x;
    const uint32_t* row = partials + (size_t)k * HBLK;
    uint32_t s = row[t] + row[t + 64] + row[t + 128] + row[t + 192];
#pragma unroll
    for (int o = 32; o; o >>= 1) s += __shfl_down(s, o);
    if (t == 0) totals[k] = s;
}

// ---------------- K3c: bucket bases + per-(bucket,block) cursors ----------------
static __global__ __launch_bounds__(256) void bucket_cursor_kernel(const uint32_t* __restrict__ partials,
                                                                   const uint32_t* __restrict__ totals,
                                                                   uint32_t* __restrict__ blockCursor,
                                                                   uint32_t* __restrict__ bucket_base) {
    __shared__ uint32_t sc[256];
    int k = blockIdx.x, t = threadIdx.x;
    uint32_t tk = (t < NBKT) ? totals[t] : 0;
    sc[t] = tk;
    __syncthreads();
    for (int o = 1; o < 256; o <<= 1) {
        uint32_t u = (t >= o) ? sc[t - o] : 0;
        __syncthreads();
        sc[t] += u;
        __syncthreads();
    }
    uint32_t incl_k = sc[k];
    uint32_t total_k = totals[k];
    uint32_t base = incl_k - total_k;
    if (t == 0) {
        bucket_base[k] = base;
        if (k == NBKT - 1) bucket_base[NBKT] = incl_k;
    }
    __syncthreads();
    uint32_t p = partials[(size_t)k * HBLK + t];
    sc[t] = p;
    __syncthreads();
    for (int o = 1; o < 256; o <<= 1) {
        uint32_t u = (t >= o) ? sc[t - o] : 0;
        __syncthreads();
        sc[t] += u;
        __syncthreads();
    }
    blockCursor[(size_t)k * HBLK + t] = base + sc[t] - p;
}

// ---------------- K4: scatter edges into bucket-ordered ebuf ----------------
static __global__ __launch_bounds__(256) void bucket_scatter_kernel(const int* __restrict__ src,
                                                                    const int* __restrict__ dst,
                                                                    const uint32_t* __restrict__ blockCursor,
                                                                    int2* __restrict__ ebuf) {
    __shared__ uint32_t cur[NBKT];
    int b = blockIdx.x, t = threadIdx.x;
    if (t < NBKT) cur[t] = blockCursor[(size_t)t * HBLK + b];
    __syncthreads();
    int base = b * EPB;
    for (int i = t; i < EPB; i += 256) {
        int s = src[base + i], d = dst[base + i];
        uint32_t p = atomicAdd(&cur[(unsigned)d >> BKT_BITS], 1u);
        ebuf[p] = make_int2(s, d);
    }
}

// ---------------- K5: per-bucket CSR build (row_ptr, inv_in, csr src-only) ----------------
static __global__ __launch_bounds__(256) void bucket_build_kernel(const int2* __restrict__ ebuf,
                                                                  const uint32_t* __restrict__ bucket_base,
                                                                  int* __restrict__ row_ptr,
                                                                  float* __restrict__ inv_in,
                                                                  int* __restrict__ csr) {
    __shared__ uint32_t h[BKT_SIZE];
    __shared__ uint32_t rs[BKT_SIZE];
    __shared__ uint32_t ps[256];
    int k = blockIdx.x, t = threadIdx.x;
    uint32_t b0 = bucket_base[k], b1 = bucket_base[k + 1];
    h[t] = 0; h[t + 256] = 0;
    __syncthreads();
    for (uint32_t i = b0 + t; i < b1; i += 256)
        atomicAdd(&h[ebuf[i].y & (BKT_SIZE - 1)], 1u);
    __syncthreads();
    uint32_t a = h[2 * t], bb = h[2 * t + 1];
    uint32_t pair = a + bb;
    ps[t] = pair;
    __syncthreads();
    for (int o = 1; o < 256; o <<= 1) {
        uint32_t u = (t >= o) ? ps[t - o] : 0;
        __syncthreads();
        ps[t] += u;
        __syncthreads();
    }
    uint32_t ex = ps[t] - pair;
    rs[2 * t] = ex;
    rs[2 * t + 1] = ex + a;
    int node0 = k * BKT_SIZE;
    if (node0 + 2 * t < N_NODES) {
        row_ptr[node0 + 2 * t] = (int)(b0 + ex);
        inv_in[node0 + 2 * t] = a ? rsqrtf((float)a) : 0.f;
    }
    if (node0 + 2 * t + 1 < N_NODES) {
        row_ptr[node0 + 2 * t + 1] = (int)(b0 + ex + a);
        inv_in[node0 + 2 * t + 1] = bb ? rsqrtf((float)bb) : 0.f;
    }
    if (k == NBKT - 1 && t == 0) row_ptr[N_NODES] = (int)b1;
    __syncthreads();
    for (uint32_t i = b0 + t; i < b1; i += 256) {
        int2 e = ebuf[i];
        int li = e.y & (BKT_SIZE - 1);
        uint32_t p = atomicAdd(&rs[li], 1u);
        csr[b0 + p] = e.x;
    }
}

// ---------------- W transpose: Wt[c][k] = fp16(W[k][c]) ----------------
static __global__ __launch_bounds__(256) void wtrans_kernel(const float* __restrict__ W,
                                                            _Float16* __restrict__ Wt) {
    int k = blockIdx.x * 2 + (threadIdx.x >> 7);          // grid 128 -> k 0..255
    int c = threadIdx.x & 127;
    Wt[(size_t)c * IN_CH + k] = (_Float16)W[(size_t)k * HID + c];
}

// ---------------- MFMA GEMM: t16[r] = fp16( (A@W)[r] * inv_out[r] ) ----------------
// BM=128, BN=128(=HID), BK=32, 4 waves 2x2, wave = 64x64 via 16x mfma_f32_16x16x32_f16
__device__ __forceinline__ int kswz(int row, int kb) {
    return (kb ^ ((row ^ (row >> 2)) & 3)) << 3;           // 8-half group offset
}

static __global__ __launch_bounds__(256) void mfma_gemm_kernel(const float* __restrict__ A,
                                                               const _Float16* __restrict__ Wt,
                                                               const float* __restrict__ inv_out,
                                                               __half* __restrict__ t16) {
    __shared__ _Float16 As[128][32];     // 8 KB, k-major, swizzled groups
    __shared__ _Float16 Bs[128][32];     // 8 KB, [col][k]
    __shared__ __half  Cs[128][HID];     // 32 KB
    __shared__ float   io[128];
    int tid = threadIdx.x;
    int brow = blockIdx.x * 128;
    if (tid < 128) {
        int r = brow + tid;
        io[tid] = (r < N_NODES) ? inv_out[r] : 0.f;
    }
    int wave = tid >> 6, lane = tid & 63;
    int wm = wave >> 1, wn = wave & 1;
    int l15 = lane & 15, l4 = lane >> 4;

    f32x4 acc[4][4] = {};
    int srow = tid >> 1;                  // staging row/col
    int sko = (tid & 1) * 16;             // staging k offset (16 floats)

    for (int k0 = 0; k0 < IN_CH; k0 += 32) {
        // ---- stage A (fp32 -> fp16) ----
        {
            float4 f[4];
            int gr = brow + srow;
            if (gr < N_NODES) {
                const float4* ap = (const float4*)&A[(size_t)gr * IN_CH + k0 + sko];
                f[0] = ap[0]; f[1] = ap[1]; f[2] = ap[2]; f[3] = ap[3];
            } else {
                f[0] = f[1] = f[2] = f[3] = make_float4(0.f, 0.f, 0.f, 0.f);
            }
#pragma unroll
            for (int g = 0; g < 2; g++) {
                _Float16 hh[8];
                float* fp = (float*)&f[2 * g];
#pragma unroll
                for (int q = 0; q < 8; q++) hh[q] = (_Float16)fp[q];
                int kb = (sko >> 3) + g;
                *(uint4*)&As[srow][kswz(srow, kb)] = *(uint4*)hh;
            }
        }
        // ---- stage B (Wt fp16, coalesced) ----
        {
            const uint4* wp = (const uint4*)&Wt[(size_t)srow * IN_CH + k0 + sko];
            uint4 u0 = wp[0], u1 = wp[1];   // 8 halfs each
            int kb = sko >> 3;
            *(uint4*)&Bs[srow][kswz(srow, kb)] = u0;
            *(uint4*)&Bs[srow][kswz(srow, kb + 1)] = u1;
        }
        __syncthreads();
        // ---- fragments + 16 MFMA ----
        f16x8 af[4], bf[4];
#pragma unroll
        for (int mt = 0; mt < 4; mt++) {
            int row = wm * 64 + mt * 16 + l15;
            af[mt] = *(f16x8*)&As[row][kswz(row, l4)];
        }
#pragma unroll
        for (int nt = 0; nt < 4; nt++) {
            int col = wn * 64 + nt * 16 + l15;
            bf[nt] = *(f16x8*)&Bs[col][kswz(col, l4)];
        }
#pragma unroll
        for (int mt = 0; mt < 4; mt++)
#pragma unroll
            for (int nt = 0; nt < 4; nt++)
                acc[mt][nt] = __builtin_amdgcn_mfma_f32_16x16x32_f16(af[mt], bf[nt], acc[mt][nt], 0, 0, 0);
        __syncthreads();
    }
    // ---- epilogue: scale + fp16 repack via LDS, coalesced store ----
#pragma unroll
    for (int mt = 0; mt < 4; mt++) {
#pragma unroll
        for (int nt = 0; nt < 4; nt++) {
#pragma unroll
            for (int r = 0; r < 4; r++) {
                int row = wm * 64 + mt * 16 + l4 * 4 + r;
                int col = wn * 64 + nt * 16 + l15;
                Cs[row][col] = __float2half(acc[mt][nt][r] * io[row]);
            }
        }
    }
    __syncthreads();
    {
        int row = tid >> 1;
        int c0 = (tid & 1) * 64;
        int gr = brow + row;
        if (gr < N_NODES) {
            uint4* s = (uint4*)&Cs[row][c0];
            uint4* d = (uint4*)&t16[(size_t)gr * HID + c0];
#pragma unroll
            for (int i = 0; i < 8; i++) d[i] = s[i];
        }
    }
}

// ---------------- zero the sentinel row N in fp16 buffers ----------------
static __global__ void zero_rows_kernel(__half* a, __half* b, __half* c) {
    int t = threadIdx.x;                 // 64 threads, row = 64 u32
    ((uint32_t*)a)[(size_t)N_NODES * 64 + t] = 0;
    ((uint32_t*)b)[(size_t)N_NODES * 64 + t] = 0;
    ((uint32_t*)c)[(size_t)N_NODES * 64 + t] = 0;
}

// ---------------- Propagation, fp16 gathers ----------------
// Wave: 4 subgroups x 16 lanes; subgroup handles one edge; lane covers 8 cols.
template <int MODE>
static __global__ __launch_bounds__(256) void prop16_kernel(const __half* __restrict__ gin,
                                                            const int* __restrict__ rp,
                                                            const int* __restrict__ cs,
                                                            const float* __restrict__ inv_in,
                                                            const float* __restrict__ inv_out,
                                                            const float* __restrict__ bias,
                                                            const __half* __restrict__ h0h,
                                                            __half* __restrict__ gout,
                                                            __half* __restrict__ h0out,
                                                            float* __restrict__ fout) {
    int wid = (int)((blockIdx.x * 256u + threadIdx.x) >> 6);
    if (wid >= N_NODES) return;
    int lane = threadIdx.x & 63;
    int sub = lane >> 4;
    int cl = lane & 15;
    int s = rp[wid], e = rp[wid + 1];
    const uint4* g4 = (const uint4*)gin;          // 16 uint4 per row

    float a[8] = {};
    for (int j = s; j < e; j += 8) {
        int j0 = j + sub, j1 = j0 + 4;
        int v0 = cs[j0], v1 = cs[j1];             // csr alloc padded by 8
        int i0 = (j0 < e) ? v0 : N_NODES;
        int i1 = (j1 < e) ? v1 : N_NODES;
        uint4 u0 = g4[(size_t)i0 * 16 + cl];
        uint4 u1 = g4[(size_t)i1 * 16 + cl];
        const __half2* p0 = (const __half2*)&u0;
        const __half2* p1 = (const __half2*)&u1;
#pragma unroll
        for (int k = 0; k < 4; k++) {
            float2 f0 = __half22float2(p0[k]);
            float2 f1 = __half22float2(p1[k]);
            a[2 * k] += f0.x + f1.x;
            a[2 * k + 1] += f0.y + f1.y;
        }
    }
#pragma unroll
    for (int k = 0; k < 8; k++) {
        a[k] += __shfl_xor(a[k], 16);
        a[k] += __shfl_xor(a[k], 32);
    }
    if (sub != 0) return;
    int c0 = cl * 8;
    if (MODE == 0) {
        float ii = inv_in[wid], io = inv_out[wid];
        float4 b0 = *(const float4*)&bias[c0];
        float4 b1 = *(const float4*)&bias[c0 + 4];
        float h[8];
        h[0] = fmaxf(a[0] * ii + b0.x, 0.f);
        h[1] = fmaxf(a[1] * ii + b0.y, 0.f);
        h[2] = fmaxf(a[2] * ii + b0.z, 0.f);
        h[3] = fmaxf(a[3] * ii + b0.w, 0.f);
        h[4] = fmaxf(a[4] * ii + b1.x, 0.f);
        h[5] = fmaxf(a[5] * ii + b1.y, 0.f);
        h[6] = fmaxf(a[6] * ii + b1.z, 0.f);
        h[7] = fmaxf(a[7] * ii + b1.w, 0.f);
        __half2 hh[4], gg[4];
#pragma unroll
        for (int k = 0; k < 4; k++) {
            hh[k] = __floats2half2_rn(h[2 * k], h[2 * k + 1]);
            gg[k] = __floats2half2_rn(h[2 * k] * io, h[2 * k + 1] * io);
        }
        ((uint4*)h0out)[(size_t)wid * 16 + cl] = *(uint4*)hh;
        ((uint4*)gout)[(size_t)wid * 16 + cl] = *(uint4*)gg;
    } else {
        float ii = inv_in[wid] * (1.f - ALPHA);
        uint4 uh = ((const uint4*)h0h)[(size_t)wid * 16 + cl];
        const __half2* ph = (const __half2*)&uh;
        float h[8];
#pragma unroll
        for (int k = 0; k < 4; k++) {
            float2 f = __half22float2(ph[k]);
            h[2 * k] = a[2 * k] * ii + ALPHA * f.x;
            h[2 * k + 1] = a[2 * k + 1] * ii + ALPHA * f.y;
        }
        if (MODE == 1) {
            float io = inv_out[wid];
            __half2 gg[4];
#pragma unroll
            for (int k = 0; k < 4; k++)
                gg[k] = __floats2half2_rn(h[2 * k] * io, h[2 * k + 1] * io);
            ((uint4*)gout)[(size_t)wid * 16 + cl] = *(uint4*)gg;
        } else {
            *(float4*)&fout[(size_t)wid * HID + c0] = make_float4(h[0], h[1], h[2], h[3]);
            *(float4*)&fout[(size_t)wid * HID + c0 + 4] = make_float4(h[4], h[5], h[6], h[7]);
        }
    }
}

// ---------------- launch ----------------
extern "C" void kernel_launch(void* const* d_in, const int* in_sizes, int n_in,
                              void* d_out, int out_size, void* d_ws, size_t ws_size,
                              hipStream_t stream) {
    const float* features = (const float*)d_in[0];
    const float* W = (const float*)d_in[1];
    const float* b = (const float*)d_in[2];
    const int* edge_index = (const int*)d_in[3];
    const int* src = edge_index;
    const int* dst = edge_index + N_EDGES;
    float* out = (float*)d_out;

    char* ws = (char*)d_ws;
    size_t off = 0;
    auto alloc = [&](size_t bytes) -> void* {
        void* p = ws + off;
        off = (off + bytes + 255) & ~(size_t)255;
        return p;
    };
    // persistent
    int* csr = (int*)alloc(((size_t)N_EDGES + 8) * 4);              // 6.4 MB
    __half* t16 = (__half*)alloc((size_t)(N_NODES + 1) * HID * 2);  // 25.6 MB
    __half* gA  = (__half*)alloc((size_t)(N_NODES + 1) * HID * 2);  // 25.6 MB
    __half* gB  = (__half*)alloc((size_t)(N_NODES + 1) * HID * 2);  // 25.6 MB
    __half* h0h = (__half*)alloc((size_t)N_NODES * HID * 2);        // 25.6 MB
    float* inv_out = (float*)alloc((size_t)N_NODES * 4);
    float* inv_in = (float*)alloc((size_t)N_NODES * 4);
    int* row_ptr = (int*)alloc((size_t)(N_NODES + 1) * 4);
    _Float16* Wt = (_Float16*)alloc((size_t)HID * IN_CH * 2);       // 64 KB
    // transient, aliased over gA+gB (consumed before first prop writes them)
    char* tb = (char*)gA;
    size_t toff = 0;
    auto talloc = [&](size_t bytes) -> void* {
        void* p = tb + toff;
        toff = (toff + bytes + 255) & ~(size_t)255;
        return p;
    };
    int2* ebuf = (int2*)talloc((size_t)N_EDGES * 8);                 // 12.8 MB
    uint16_t* srcpart = (uint16_t*)talloc((size_t)DC * N_NODES * 2); // 6.4 MB
    uint32_t* partials = (uint32_t*)talloc((size_t)NBKT * HBLK * 4);
    uint32_t* blockCursor = (uint32_t*)talloc((size_t)NBKT * HBLK * 4);
    uint32_t* totals = (uint32_t*)talloc(NBKT * 4);
    uint32_t* bucket_base = (uint32_t*)talloc((NBKT + 1) * 4);

    bucket_hist_kernel<<<HBLK, 256, 0, stream>>>(dst, partials);
    srcdeg_hist_kernel<<<DR * DC, 256, 0, stream>>>(src, srcpart);
    srcdeg_reduce_kernel<<<(N_NODES + 255) / 256, 256, 0, stream>>>(srcpart, inv_out);
    bucket_totals_kernel<<<NBKT, 64, 0, stream>>>(partials, totals);
    bucket_cursor_kernel<<<NBKT, 256, 0, stream>>>(partials, totals, blockCursor, bucket_base);
    bucket_scatter_kernel<<<HBLK, 256, 0, stream>>>(src, dst, blockCursor, ebuf);
    bucket_build_kernel<<<NBKT, 256, 0, stream>>>(ebuf, bucket_base, row_ptr, inv_in, csr);

    wtrans_kernel<<<128, 256, 0, stream>>>(W, Wt);
    mfma_gemm_kernel<<<(N_NODES + 127) / 128, 256, 0, stream>>>(features, Wt, inv_out, t16);
    zero_rows_kernel<<<1, 64, 0, stream>>>(t16, gA, gB);

    int pb = (int)(((size_t)N_NODES * 64) / 256);
    // GraphConv epilogue: h0h + g0 (into gA)
    prop16_kernel<0><<<pb, 256, 0, stream>>>(t16, row_ptr, csr, inv_in, inv_out, b, nullptr,
                                             gA, h0h, nullptr);
    // APPNP steps 0..8 (fp16 ping-pong), step 9 writes fp32 out
    const __half* cur = gA;
    for (int t = 0; t < K_STEPS - 1; t++) {
        __half* nxt = (t & 1) ? gA : gB;
        prop16_kernel<1><<<pb, 256, 0, stream>>>(cur, row_ptr, csr, inv_in, inv_out, nullptr, h0h,
                                                 nxt, nullptr, nullptr);
        cur = nxt;
    }
    prop16_kernel<2><<<pb, 256, 0, stream>>>(cur, row_ptr, csr, inv_in, inv_out, nullptr, h0h,
                                             nullptr, nullptr, out);
}

// Round 6
// 796.248 us; speedup vs baseline: 2.1455x; 1.0529x over previous
//
#include <hip/hip_runtime.h>
#include <hip/hip_fp16.h>
#include <stdint.h>

#define N_NODES 100000
#define N_EDGES 1600000
#define IN_CH 256
#define HID 128
#define K_STEPS 10
#define ALPHA 0.1f

// dst bucketing
#define BKT_BITS 9
#define BKT_SIZE 512
#define NBKT 196                         // ceil(100000/512)
#define HBLK 256                         // blocks for hist/scatter
#define EPB (N_EDGES / HBLK)             // 6250 edges per block

// src-degree histogram partitioning
#define DR 8                             // node ranges
#define DRS (N_NODES / DR)               // 12500 nodes per range
#define DC 64                            // edge chunks
#define DCE (N_EDGES / DC)               // 25000 edges per chunk

typedef _Float16 f16x8 __attribute__((ext_vector_type(8)));
typedef float f32x4 __attribute__((ext_vector_type(4)));

// ---------------- K1: per-block bucket histogram (dst) ----------------
static __global__ __launch_bounds__(256) void bucket_hist_kernel(const int* __restrict__ dst,
                                                                 uint32_t* __restrict__ partials) {
    __shared__ uint32_t h[NBKT];
    int b = blockIdx.x, t = threadIdx.x;
    if (t < NBKT) h[t] = 0;
    __syncthreads();
    int base = b * EPB;
    for (int i = t; i < EPB; i += 256)
        atomicAdd(&h[(unsigned)dst[base + i] >> BKT_BITS], 1u);
    __syncthreads();
    if (t < NBKT) partials[t * HBLK + b] = h[t];          // [bucket][block]
}

// ---------------- K2a: src-degree partial histograms (packed u16 in LDS) ----------------
// grid DR*DC = 512 blocks; 25 KB LDS -> ~6 blocks/CU; int4 loads for MLP.
static __global__ __launch_bounds__(256) void srcdeg_hist_kernel(const int* __restrict__ src,
                                                                 uint16_t* __restrict__ srcpart) {
    __shared__ uint32_t h[DRS / 2];                        // 25 KB, u16 pairs
    int r = blockIdx.x >> 6;                               // range 0..7
    int c = blockIdx.x & 63;                               // chunk 0..63
    int t = threadIdx.x;
    for (int i = t; i < DRS / 2; i += 256) h[i] = 0;
    __syncthreads();
    int lo = r * DRS;
    const int4* sp = (const int4*)(src + (size_t)c * DCE);
    for (int i = t; i < DCE / 4; i += 256) {
        int4 v = sp[i];
        unsigned a0 = (unsigned)(v.x - lo);
        unsigned a1 = (unsigned)(v.y - lo);
        unsigned a2 = (unsigned)(v.z - lo);
        unsigned a3 = (unsigned)(v.w - lo);
        if (a0 < DRS) atomicAdd(&h[a0 >> 1], 1u << ((a0 & 1) * 16));
        if (a1 < DRS) atomicAdd(&h[a1 >> 1], 1u << ((a1 & 1) * 16));
        if (a2 < DRS) atomicAdd(&h[a2 >> 1], 1u << ((a2 & 1) * 16));
        if (a3 < DRS) atomicAdd(&h[a3 >> 1], 1u << ((a3 & 1) * 16));
    }
    __syncthreads();
    uint32_t* pp = (uint32_t*)(srcpart + (size_t)c * N_NODES + lo);
    for (int i = t; i < DRS / 2; i += 256) pp[i] = h[i];
}

// ---------------- K2b: reduce packed partials -> inv_out (2 nodes/thread) ----------------
static __global__ void srcdeg_reduce_kernel(const uint16_t* __restrict__ srcpart,
                                            float* __restrict__ inv_out) {
    int n2 = blockIdx.x * 256 + threadIdx.x;               // pair index
    if (n2 >= N_NODES / 2) return;
    uint32_t lo = 0, hi = 0;
#pragma unroll
    for (int c = 0; c < DC; c++) {
        uint32_t u = *(const uint32_t*)&srcpart[(size_t)c * N_NODES + 2 * n2];
        lo += u & 0xffffu;
        hi += u >> 16;
    }
    inv_out[2 * n2] = lo ? rsqrtf((float)lo) : 0.f;
    inv_out[2 * n2 + 1] = hi ? rsqrtf((float)hi) : 0.f;
}

// ---------------- K3a: per-bucket totals ----------------
static __global__ __launch_bounds__(64) void bucket_totals_kernel(const uint32_t* __restrict__ partials,
                                                                  uint32_t* __restrict__ totals) {
    int k = blockIdx.x, t = threadIdx.x;
    const uint32_t* row = partials + (size_t)k * HBLK;
    uint32_t s = row[t] + row[t + 64] + row[t + 128] + row[t + 192];
#pragma unroll
    for (int o = 32; o; o >>= 1) s += __shfl_down(s, o);
    if (t == 0) totals[k] = s;
}

// ---------------- K3c: bucket bases + per-(bucket,block) cursors ----------------
static __global__ __launch_bounds__(256) void bucket_cursor_kernel(const uint32_t* __restrict__ partials,
                                                                   const uint32_t* __restrict__ totals,
                                                                   uint32_t* __restrict__ blockCursor,
                                                                   uint32_t* __restrict__ bucket_base) {
    __shared__ uint32_t sc[256];
    int k = blockIdx.x, t = threadIdx.x;
    uint32_t tk = (t < NBKT) ? totals[t] : 0;
    sc[t] = tk;
    __syncthreads();
    for (int o = 1; o < 256; o <<= 1) {
        uint32_t u = (t >= o) ? sc[t - o] : 0;
        __syncthreads();
        sc[t] += u;
        __syncthreads();
    }
    uint32_t incl_k = sc[k];
    uint32_t total_k = totals[k];
    uint32_t base = incl_k - total_k;
    if (t == 0) {
        bucket_base[k] = base;
        if (k == NBKT - 1) bucket_base[NBKT] = incl_k;
    }
    __syncthreads();
    uint32_t p = partials[(size_t)k * HBLK + t];
    sc[t] = p;
    __syncthreads();
    for (int o = 1; o < 256; o <<= 1) {
        uint32_t u = (t >= o) ? sc[t - o] : 0;
        __syncthreads();
        sc[t] += u;
        __syncthreads();
    }
    blockCursor[(size_t)k * HBLK + t] = base + sc[t] - p;
}

// ---------------- K4: scatter edges into bucket-ordered ebuf ----------------
static __global__ __launch_bounds__(256) void bucket_scatter_kernel(const int* __restrict__ src,
                                                                    const int* __restrict__ dst,
                                                                    const uint32_t* __restrict__ blockCursor,
                                                                    int2* __restrict__ ebuf) {
    __shared__ uint32_t cur[NBKT];
    int b = blockIdx.x, t = threadIdx.x;
    if (t < NBKT) cur[t] = blockCursor[(size_t)t * HBLK + b];
    __syncthreads();
    int base = b * EPB;
    for (int i = t; i < EPB; i += 256) {
        int s = src[base + i], d = dst[base + i];
        uint32_t p = atomicAdd(&cur[(unsigned)d >> BKT_BITS], 1u);
        ebuf[p] = make_int2(s, d);
    }
}

// ---------------- K5: per-bucket CSR build (row_ptr, inv_in, csr src-only) ----------------
static __global__ __launch_bounds__(256) void bucket_build_kernel(const int2* __restrict__ ebuf,
                                                                  const uint32_t* __restrict__ bucket_base,
                                                                  int* __restrict__ row_ptr,
                                                                  float* __restrict__ inv_in,
                                                                  int* __restrict__ csr) {
    __shared__ uint32_t h[BKT_SIZE];
    __shared__ uint32_t rs[BKT_SIZE];
    __shared__ uint32_t ps[256];
    int k = blockIdx.x, t = threadIdx.x;
    uint32_t b0 = bucket_base[k], b1 = bucket_base[k + 1];
    h[t] = 0; h[t + 256] = 0;
    __syncthreads();
    for (uint32_t i = b0 + t; i < b1; i += 256)
        atomicAdd(&h[ebuf[i].y & (BKT_SIZE - 1)], 1u);
    __syncthreads();
    uint32_t a = h[2 * t], bb = h[2 * t + 1];
    uint32_t pair = a + bb;
    ps[t] = pair;
    __syncthreads();
    for (int o = 1; o < 256; o <<= 1) {
        uint32_t u = (t >= o) ? ps[t - o] : 0;
        __syncthreads();
        ps[t] += u;
        __syncthreads();
    }
    uint32_t ex = ps[t] - pair;
    rs[2 * t] = ex;
    rs[2 * t + 1] = ex + a;
    int node0 = k * BKT_SIZE;
    if (node0 + 2 * t < N_NODES) {
        row_ptr[node0 + 2 * t] = (int)(b0 + ex);
        inv_in[node0 + 2 * t] = a ? rsqrtf((float)a) : 0.f;
    }
    if (node0 + 2 * t + 1 < N_NODES) {
        row_ptr[node0 + 2 * t + 1] = (int)(b0 + ex + a);
        inv_in[node0 + 2 * t + 1] = bb ? rsqrtf((float)bb) : 0.f;
    }
    if (k == NBKT - 1 && t == 0) row_ptr[N_NODES] = (int)b1;
    __syncthreads();
    for (uint32_t i = b0 + t; i < b1; i += 256) {
        int2 e = ebuf[i];
        int li = e.y & (BKT_SIZE - 1);
        uint32_t p = atomicAdd(&rs[li], 1u);
        csr[b0 + p] = e.x;
    }
}

// ---------------- W transpose: Wt[c][k] = fp16(W[k][c]) ----------------
static __global__ __launch_bounds__(256) void wtrans_kernel(const float* __restrict__ W,
                                                            _Float16* __restrict__ Wt) {
    int k = blockIdx.x * 2 + (threadIdx.x >> 7);          // grid 128 -> k 0..255
    int c = threadIdx.x & 127;
    Wt[(size_t)c * IN_CH + k] = (_Float16)W[(size_t)k * HID + c];
}

// ---------------- MFMA GEMM: t16[r] = fp16( (A@W)[r] * inv_out[r] ) ----------------
__device__ __forceinline__ int kswz(int row, int kb) {
    return (kb ^ ((row ^ (row >> 2)) & 3)) << 3;           // 8-half group offset
}

static __global__ __launch_bounds__(256) void mfma_gemm_kernel(const float* __restrict__ A,
                                                               const _Float16* __restrict__ Wt,
                                                               const float* __restrict__ inv_out,
                                                               __half* __restrict__ t16) {
    __shared__ _Float16 As[128][32];     // 8 KB, k-major, swizzled groups
    __shared__ _Float16 Bs[128][32];     // 8 KB, [col][k]
    __shared__ __half  Cs[128][HID];     // 32 KB
    __shared__ float   io[128];
    int tid = threadIdx.x;
    int brow = blockIdx.x * 128;
    if (tid < 128) {
        int r = brow + tid;
        io[tid] = (r < N_NODES) ? inv_out[r] : 0.f;
    }
    int wave = tid >> 6, lane = tid & 63;
    int wm = wave >> 1, wn = wave & 1;
    int l15 = lane & 15, l4 = lane >> 4;

    f32x4 acc[4][4] = {};
    int srow = tid >> 1;
    int sko = (tid & 1) * 16;

    for (int k0 = 0; k0 < IN_CH; k0 += 32) {
        {
            float4 f[4];
            int gr = brow + srow;
            if (gr < N_NODES) {
                const float4* ap = (const float4*)&A[(size_t)gr * IN_CH + k0 + sko];
                f[0] = ap[0]; f[1] = ap[1]; f[2] = ap[2]; f[3] = ap[3];
            } else {
                f[0] = f[1] = f[2] = f[3] = make_float4(0.f, 0.f, 0.f, 0.f);
            }
#pragma unroll
            for (int g = 0; g < 2; g++) {
                _Float16 hh[8];
                float* fp = (float*)&f[2 * g];
#pragma unroll
                for (int q = 0; q < 8; q++) hh[q] = (_Float16)fp[q];
                int kb = (sko >> 3) + g;
                *(uint4*)&As[srow][kswz(srow, kb)] = *(uint4*)hh;
            }
        }
        {
            const uint4* wp = (const uint4*)&Wt[(size_t)srow * IN_CH + k0 + sko];
            uint4 u0 = wp[0], u1 = wp[1];
            int kb = sko >> 3;
            *(uint4*)&Bs[srow][kswz(srow, kb)] = u0;
            *(uint4*)&Bs[srow][kswz(srow, kb + 1)] = u1;
        }
        __syncthreads();
        f16x8 af[4], bf[4];
#pragma unroll
        for (int mt = 0; mt < 4; mt++) {
            int row = wm * 64 + mt * 16 + l15;
            af[mt] = *(f16x8*)&As[row][kswz(row, l4)];
        }
#pragma unroll
        for (int nt = 0; nt < 4; nt++) {
            int col = wn * 64 + nt * 16 + l15;
            bf[nt] = *(f16x8*)&Bs[col][kswz(col, l4)];
        }
#pragma unroll
        for (int mt = 0; mt < 4; mt++)
#pragma unroll
            for (int nt = 0; nt < 4; nt++)
                acc[mt][nt] = __builtin_amdgcn_mfma_f32_16x16x32_f16(af[mt], bf[nt], acc[mt][nt], 0, 0, 0);
        __syncthreads();
    }
#pragma unroll
    for (int mt = 0; mt < 4; mt++) {
#pragma unroll
        for (int nt = 0; nt < 4; nt++) {
#pragma unroll
            for (int r = 0; r < 4; r++) {
                int row = wm * 64 + mt * 16 + l4 * 4 + r;
                int col = wn * 64 + nt * 16 + l15;
                Cs[row][col] = __float2half(acc[mt][nt][r] * io[row]);
            }
        }
    }
    __syncthreads();
    {
        int row = tid >> 1;
        int c0 = (tid & 1) * 64;
        int gr = brow + row;
        if (gr < N_NODES) {
            uint4* s = (uint4*)&Cs[row][c0];
            uint4* d = (uint4*)&t16[(size_t)gr * HID + c0];
#pragma unroll
            for (int i = 0; i < 8; i++) d[i] = s[i];
        }
    }
}

// ---------------- zero the sentinel row N in fp16 buffers ----------------
static __global__ void zero_rows_kernel(__half* a, __half* b, __half* c) {
    int t = threadIdx.x;                 // 64 threads, row = 64 u32
    ((uint32_t*)a)[(size_t)N_NODES * 64 + t] = 0;
    ((uint32_t*)b)[(size_t)N_NODES * 64 + t] = 0;
    ((uint32_t*)c)[(size_t)N_NODES * 64 + t] = 0;
}

// ---------------- Propagation, fp16 gathers ----------------
// Wave: 4 subgroups x 16 lanes; subgroup handles one edge; lane covers 8 cols.
template <int MODE>
static __global__ __launch_bounds__(256) void prop16_kernel(const __half* __restrict__ gin,
                                                            const int* __restrict__ rp,
                                                            const int* __restrict__ cs,
                                                            const float* __restrict__ inv_in,
                                                            const float* __restrict__ inv_out,
                                                            const float* __restrict__ bias,
                                                            const __half* __restrict__ h0h,
                                                            __half* __restrict__ gout,
                                                            __half* __restrict__ h0out,
                                                            float* __restrict__ fout) {
    int wid = (int)((blockIdx.x * 256u + threadIdx.x) >> 6);
    if (wid >= N_NODES) return;
    int lane = threadIdx.x & 63;
    int sub = lane >> 4;
    int cl = lane & 15;
    int s = rp[wid], e = rp[wid + 1];
    const uint4* g4 = (const uint4*)gin;          // 16 uint4 per row

    float a[8] = {};
    for (int j = s; j < e; j += 8) {
        int j0 = j + sub, j1 = j0 + 4;
        int v0 = cs[j0], v1 = cs[j1];             // csr alloc padded by 8
        int i0 = (j0 < e) ? v0 : N_NODES;
        int i1 = (j1 < e) ? v1 : N_NODES;
        uint4 u0 = g4[(size_t)i0 * 16 + cl];
        uint4 u1 = g4[(size_t)i1 * 16 + cl];
        const __half2* p0 = (const __half2*)&u0;
        const __half2* p1 = (const __half2*)&u1;
#pragma unroll
        for (int k = 0; k < 4; k++) {
            float2 f0 = __half22float2(p0[k]);
            float2 f1 = __half22float2(p1[k]);
            a[2 * k] += f0.x + f1.x;
            a[2 * k + 1] += f0.y + f1.y;
        }
    }
#pragma unroll
    for (int k = 0; k < 8; k++) {
        a[k] += __shfl_xor(a[k], 16);
        a[k] += __shfl_xor(a[k], 32);
    }
    if (sub != 0) return;
    int c0 = cl * 8;
    if (MODE == 0) {
        float ii = inv_in[wid], io = inv_out[wid];
        float4 b0 = *(const float4*)&bias[c0];
        float4 b1 = *(const float4*)&bias[c0 + 4];
        float h[8];
        h[0] = fmaxf(a[0] * ii + b0.x, 0.f);
        h[1] = fmaxf(a[1] * ii + b0.y, 0.f);
        h[2] = fmaxf(a[2] * ii + b0.z, 0.f);
        h[3] = fmaxf(a[3] * ii + b0.w, 0.f);
        h[4] = fmaxf(a[4] * ii + b1.x, 0.f);
        h[5] = fmaxf(a[5] * ii + b1.y, 0.f);
        h[6] = fmaxf(a[6] * ii + b1.z, 0.f);
        h[7] = fmaxf(a[7] * ii + b1.w, 0.f);
        __half2 hh[4], gg[4];
#pragma unroll
        for (int k = 0; k < 4; k++) {
            hh[k] = __floats2half2_rn(h[2 * k], h[2 * k + 1]);
            gg[k] = __floats2half2_rn(h[2 * k] * io, h[2 * k + 1] * io);
        }
        ((uint4*)h0out)[(size_t)wid * 16 + cl] = *(uint4*)hh;
        ((uint4*)gout)[(size_t)wid * 16 + cl] = *(uint4*)gg;
    } else {
        float ii = inv_in[wid] * (1.f - ALPHA);
        uint4 uh = ((const uint4*)h0h)[(size_t)wid * 16 + cl];
        const __half2* ph = (const __half2*)&uh;
        float h[8];
#pragma unroll
        for (int k = 0; k < 4; k++) {
            float2 f = __half22float2(ph[k]);
            h[2 * k] = a[2 * k] * ii + ALPHA * f.x;
            h[2 * k + 1] = a[2 * k + 1] * ii + ALPHA * f.y;
        }
        if (MODE == 1) {
            float io = inv_out[wid];
            __half2 gg[4];
#pragma unroll
            for (int k = 0; k < 4; k++)
                gg[k] = __floats2half2_rn(h[2 * k] * io, h[2 * k + 1] * io);
            ((uint4*)gout)[(size_t)wid * 16 + cl] = *(uint4*)gg;
        } else {
            *(float4*)&fout[(size_t)wid * HID + c0] = make_float4(h[0], h[1], h[2], h[3]);
            *(float4*)&fout[(size_t)wid * HID + c0 + 4] = make_float4(h[4], h[5], h[6], h[7]);
        }
    }
}

// ---------------- launch ----------------
extern "C" void kernel_launch(void* const* d_in, const int* in_sizes, int n_in,
                              void* d_out, int out_size, void* d_ws, size_t ws_size,
                              hipStream_t stream) {
    const float* features = (const float*)d_in[0];
    const float* W = (const float*)d_in[1];
    const float* b = (const float*)d_in[2];
    const int* edge_index = (const int*)d_in[3];
    const int* src = edge_index;
    const int* dst = edge_index + N_EDGES;
    float* out = (float*)d_out;

    char* ws = (char*)d_ws;
    size_t off = 0;
    auto alloc = [&](size_t bytes) -> void* {
        void* p = ws + off;
        off = (off + bytes + 255) & ~(size_t)255;
        return p;
    };
    // persistent
    int* csr = (int*)alloc(((size_t)N_EDGES + 8) * 4);              // 6.4 MB
    __half* t16 = (__half*)alloc((size_t)(N_NODES + 1) * HID * 2);  // 25.6 MB
    __half* gA  = (__half*)alloc((size_t)(N_NODES + 1) * HID * 2);  // 25.6 MB
    __half* gB  = (__half*)alloc((size_t)(N_NODES + 1) * HID * 2);  // 25.6 MB
    __half* h0h = (__half*)alloc((size_t)N_NODES * HID * 2);        // 25.6 MB
    float* inv_out = (float*)alloc((size_t)N_NODES * 4);
    float* inv_in = (float*)alloc((size_t)N_NODES * 4);
    int* row_ptr = (int*)alloc((size_t)(N_NODES + 1) * 4);
    _Float16* Wt = (_Float16*)alloc((size_t)HID * IN_CH * 2);       // 64 KB
    // transient, aliased over gA+gB (consumed before first prop writes them)
    char* tb = (char*)gA;
    size_t toff = 0;
    auto talloc = [&](size_t bytes) -> void* {
        void* p = tb + toff;
        toff = (toff + bytes + 255) & ~(size_t)255;
        return p;
    };
    int2* ebuf = (int2*)talloc((size_t)N_EDGES * 8);                 // 12.8 MB
    uint16_t* srcpart = (uint16_t*)talloc((size_t)DC * N_NODES * 2); // 12.8 MB
    uint32_t* partials = (uint32_t*)talloc((size_t)NBKT * HBLK * 4);
    uint32_t* blockCursor = (uint32_t*)talloc((size_t)NBKT * HBLK * 4);
    uint32_t* totals = (uint32_t*)talloc(NBKT * 4);
    uint32_t* bucket_base = (uint32_t*)talloc((NBKT + 1) * 4);

    bucket_hist_kernel<<<HBLK, 256, 0, stream>>>(dst, partials);
    srcdeg_hist_kernel<<<DR * DC, 256, 0, stream>>>(src, srcpart);
    srcdeg_reduce_kernel<<<(N_NODES / 2 + 255) / 256, 256, 0, stream>>>(srcpart, inv_out);
    bucket_totals_kernel<<<NBKT, 64, 0, stream>>>(partials, totals);
    bucket_cursor_kernel<<<NBKT, 256, 0, stream>>>(partials, totals, blockCursor, bucket_base);
    bucket_scatter_kernel<<<HBLK, 256, 0, stream>>>(src, dst, blockCursor, ebuf);
    bucket_build_kernel<<<NBKT, 256, 0, stream>>>(ebuf, bucket_base, row_ptr, inv_in, csr);

    wtrans_kernel<<<128, 256, 0, stream>>>(W, Wt);
    mfma_gemm_kernel<<<(N_NODES + 127) / 128, 256, 0, stream>>>(features, Wt, inv_out, t16);
    zero_rows_kernel<<<1, 64, 0, stream>>>(t16, gA, gB);

    int pb = (int)(((size_t)N_NODES * 64) / 256);
    // GraphConv epilogue: h0h + g0 (into gA)
    prop16_kernel<0><<<pb, 256, 0, stream>>>(t16, row_ptr, csr, inv_in, inv_out, b, nullptr,
                                             gA, h0h, nullptr);
    // APPNP steps 0..8 (fp16 ping-pong), step 9 writes fp32 out
    const __half* cur = gA;
    for (int t = 0; t < K_STEPS - 1; t++) {
        __half* nxt = (t & 1) ? gA : gB;
        prop16_kernel<1><<<pb, 256, 0, stream>>>(cur, row_ptr, csr, inv_in, inv_out, nullptr, h0h,
                                                 nxt, nullptr, nullptr);
        cur = nxt;
    }
    prop16_kernel<2><<<pb, 256, 0, stream>>>(cur, row_ptr, csr, inv_in, inv_out, nullptr, h0h,
                                             nullptr, nullptr, out);
}